// Round 7
// baseline (253.323 us; speedup 1.0000x reference)
//
#include <hip/hip_runtime.h>

// Problem constants (B,N,T,F,H,R) = (32,1024,32,5,64,5)
constexpr int Bc = 32, Nc = 1024, Tc = 32, Fc = 5, Hc = 64;
constexpr int BNc = Bc * Nc;   // 32768 sequences

#define DEVFN __device__ __forceinline__

typedef _Float16 f16x8 __attribute__((ext_vector_type(8)));
typedef float    f32x16 __attribute__((ext_vector_type(16)));

DEVFN float fast_rcp(float x) { return __builtin_amdgcn_rcpf(x); }
DEVFN float tanh_fast(float x) { return 1.f - 2.f * fast_rcp(__expf(2.f * x) + 1.f); }

// ---------------- Kernel 1: fused LSTM + temporal attention (MFMA) ----------
// Block = 256 thr (4 waves) x 32 seqs; wave w owns units [16w, 16w+16) via a
// ROW-PERMUTED weight matrix: virtual row r = 4*u_loc + g within a 32-row
// tile jt (u = 8*jt + u_loc). D C-layout row=(reg&3)+8*(reg>>2)+4*hi then
// gives each lane all 4 gates of units u_loc = 2*(reg>>2)+hi -> lane-local
// cell update, 8 cells/lane, 56 trans/lane/t. 12 waves/CU (launch_bounds 3).
// h exchange: shfl_xor(32) pair-swap -> each lane holds 8 contiguous units ->
// one b128 XOR-swizzled LDS write + 4 b128 reads per t.
__global__ __launch_bounds__(256, 3) void lstm_attn_kernel(
    const float* __restrict__ x,      // [BN, T, F]
    const float* __restrict__ Wih,    // [4H, F]
    const float* __restrict__ Whh,    // [4H, H]
    const float* __restrict__ bih,    // [4H]
    const float* __restrict__ bhh,    // [4H]
    const float* __restrict__ attn_w, // [H]
    const float* __restrict__ attn_b, // [1]
    _Float16* __restrict__ E16,       // [B*N, H] fp16 row-major
    _Float16* __restrict__ ET)        // [B][H][N] fp16 transposed
{
    constexpr int XP = 164;                      // x pitch (halves)
    __shared__ __align__(16) _Float16 xs[32 * XP];    // 10.5 KB; aliased w/ es
    __shared__ __align__(16) _Float16 hb[2][32 * 64]; // 8 KB h exchange
    __shared__ float ap[4][32];                  // attn partials per wave
    float* es = (float*)xs;                      // [32][65] epilogue bounce

    const int tid  = threadIdx.x;
    const int w    = tid >> 6;                   // wave id (0..3)
    const int lane = tid & 63;
    const int m    = lane & 31;                  // seq column
    const int hi   = lane >> 5;

    // ---- stage x (fp32 -> fp16 LDS) ----
    const float* xg = x + (size_t)blockIdx.x * 32 * Tc * Fc;
    for (int i = tid; i < 32 * 160; i += 256) {
        int mm = i / 160, o = i - mm * 160;
        xs[mm * XP + o] = (_Float16)xg[i];
    }

    // ---- A fragments: tiles jt = 2w+tt; lane row r=m: g=m&3, u_loc=m>>2 ----
    f16x8 af[2][5];
    #pragma unroll
    for (int tt = 0; tt < 2; ++tt) {
        const int jt = 2 * w + tt;
        const int j  = 64 * (m & 3) + 8 * jt + (m >> 2);  // orig row 64g+u
        #pragma unroll
        for (int kt = 0; kt < 4; ++kt) {
            const float* wp = Whh + j * 64 + kt * 16 + 8 * hi;
            float4 u0 = *(const float4*)wp;
            float4 u1 = *(const float4*)(wp + 4);
            af[tt][kt] = f16x8{(_Float16)u0.x, (_Float16)u0.y, (_Float16)u0.z, (_Float16)u0.w,
                               (_Float16)u1.x, (_Float16)u1.y, (_Float16)u1.z, (_Float16)u1.w};
        }
        float v[8];
        #pragma unroll
        for (int e = 0; e < 5; ++e) v[e] = Wih[j * Fc + e];
        v[5] = bih[j] + bhh[j]; v[6] = 0.f; v[7] = 0.f;
        #pragma unroll
        for (int e = 0; e < 8; ++e) {
            float z = hi ? 0.f : v[e];
            af[tt][4][e] = (_Float16)z;
        }
    }

    // attention weights for owned cells: u = 16w + 8tt + 2a + hi
    float aw_own[8];
    #pragma unroll
    for (int tt = 0; tt < 2; ++tt)
        #pragma unroll
        for (int a = 0; a < 4; ++a)
            aw_own[tt * 4 + a] = attn_w[16 * w + 8 * tt + 2 * a + hi];
    const float ab = attn_b[0];

    float hcur[8], cst[8], oacc[8];
    #pragma unroll
    for (int i = 0; i < 8; ++i) { hcur[i] = 0.f; cst[i] = 0.f; oacc[i] = 0.f; }
    float lsum = 0.f;

    f32x16 zero16 = {0,0,0,0,0,0,0,0,0,0,0,0,0,0,0,0};
    const int xrow = m * XP;
    const int sw8  = m & 7;                      // 16B-chunk XOR swizzle
    __syncthreads();

    // ---- initial B fragments: h(0)=0 in registers, x(0) row ----
    f16x8 bf[5];
    #pragma unroll
    for (int kt = 0; kt < 4; ++kt)
        #pragma unroll
        for (int e = 0; e < 8; ++e) bf[kt][e] = (_Float16)0.f;
    #pragma unroll
    for (int e = 0; e < 8; ++e) bf[4][e] = (_Float16)0.f;
    if (!hi) {
        #pragma unroll
        for (int e = 0; e < 5; ++e) bf[4][e] = xs[xrow + e];
        bf[4][5] = (_Float16)1.f;
    }

    #pragma unroll 1
    for (int t = 0; t < Tc; ++t) {
        // ---- gates: 2 tiles x 5 k-tiles ----
        f32x16 acc[2];
        #pragma unroll
        for (int tt = 0; tt < 2; ++tt) {
            acc[tt] = __builtin_amdgcn_mfma_f32_32x32x16_f16(af[tt][0], bf[0], zero16, 0, 0, 0);
            #pragma unroll
            for (int kt = 1; kt < 5; ++kt)
                acc[tt] = __builtin_amdgcn_mfma_f32_32x32x16_f16(af[tt][kt], bf[kt], acc[tt], 0, 0, 0);
        }
        // ---- cell update: gates of cell (tt,a) at acc[tt][4a+g] ----
        float attnp = 0.f;
        #pragma unroll
        for (int tt = 0; tt < 2; ++tt)
            #pragma unroll
            for (int a = 0; a < 4; ++a) {
                const int ci = tt * 4 + a;
                float ei = __expf(-acc[tt][4 * a + 0]);
                float ef = __expf(-acc[tt][4 * a + 1]);
                float Eg = __expf(2.f * acc[tt][4 * a + 2]);
                float eo = __expf(-acc[tt][4 * a + 3]);
                float u  = 1.f + ei;
                float v  = 1.f + ef;
                float wq = Eg + 1.f;
                float z  = Eg - 1.f;
                float t1 = u * wq;
                float num = fmaf(cst[ci], t1, z * v);
                float cn = num * fast_rcp(t1 * v);
                cst[ci] = cn;
                float E2 = __expf(2.f * cn);
                float hv = (E2 - 1.f) * fast_rcp((E2 + 1.f) * (1.f + eo));
                hcur[ci] = hv;
                attnp = fmaf(hv, aw_own[ci], attnp);
            }
        // ---- publish h: pair-swap so each lane holds 8 contiguous units ----
        // hi=0 holds evens of both tiles, hi=1 odds. Swap: hi=0 sends tile-1
        // evens / receives tile-0 odds -> full tile 2w; hi=1 -> tile 2w+1.
        {
            float recv[4];
            #pragma unroll
            for (int a = 0; a < 4; ++a) {
                float send = hcur[(hi ? 0 : 1) * 4 + a];
                recv[a] = __shfl_xor(send, 32);
            }
            f16x8 pk;
            #pragma unroll
            for (int a = 0; a < 4; ++a) {
                pk[2 * a]     = (_Float16)(hi ? recv[a]      : hcur[a]);
                pk[2 * a + 1] = (_Float16)(hi ? hcur[4 + a]  : recv[a]);
            }
            *(f16x8*)&hb[t & 1][m * 64 + (((2 * w + hi) ^ sw8) * 8)] = pk;
        }
        attnp += __shfl_xor(attnp, 32);
        if (!hi) ap[w][m] = attnp;
        __syncthreads();
        // ---- score + online accumulation ----
        float sc = tanh_fast(ap[0][m] + ap[1][m] + ap[2][m] + ap[3][m] + ab);
        float ew = __expf(sc);
        lsum += ew;
        #pragma unroll
        for (int i = 0; i < 8; ++i) oacc[i] = fmaf(ew, hcur[i], oacc[i]);
        // ---- next B fragments ----
        if (t != Tc - 1) {
            const _Float16* hr = &hb[t & 1][0];
            #pragma unroll
            for (int kt = 0; kt < 4; ++kt)
                bf[kt] = *(const f16x8*)&hr[m * 64 + (((2 * kt + hi) ^ sw8) * 8)];
            if (!hi) {
                #pragma unroll
                for (int e = 0; e < 5; ++e) bf[4][e] = xs[xrow + (t + 1) * Fc + e];
                bf[4][5] = (_Float16)1.f;
            }
        }
    }

    // ---- epilogue: es[m][u] = oacc/lsum, then E16 + ET ----
    __syncthreads();                    // xs reads done before aliasing
    const float li = fast_rcp(lsum);
    #pragma unroll
    for (int tt = 0; tt < 2; ++tt)
        #pragma unroll
        for (int a = 0; a < 4; ++a) {
            int u = 16 * w + 8 * tt + 2 * a + hi;
            es[m * 65 + u] = oacc[tt * 4 + a] * li;
        }
    __syncthreads();

    uint* E16u = (uint*)E16 + (size_t)blockIdx.x * 32 * 32;
    for (int idx = tid; idx < 32 * 32; idx += 256) {
        int mm = idx >> 5, hp = idx & 31;
        union { _Float16 h2[2]; uint u; } cv;
        cv.h2[0] = (_Float16)es[mm * 65 + 2 * hp];
        cv.h2[1] = (_Float16)es[mm * 65 + 2 * hp + 1];
        E16u[idx] = cv.u;
    }
    const int bb_ = blockIdx.x >> 5, n0d = (blockIdx.x & 31) * 16;
    uint* ETu = (uint*)ET;
    for (int idx = tid; idx < 64 * 16; idx += 256) {
        int h = idx >> 4, c = idx & 15;
        union { _Float16 h2[2]; uint u; } cv;
        cv.h2[0] = (_Float16)es[(2 * c) * 65 + h];
        cv.h2[1] = (_Float16)es[(2 * c + 1) * 65 + h];
        ETu[((size_t)bb_ * 64 + h) * 512 + n0d + c] = cv.u;
    }
}

// ---------------- Kernel 2: edge coefficients (packed) + degree -------------
__global__ __launch_bounds__(256) void coefq_kernel(
    const float* __restrict__ A,     // [N, N, R]
    const float* __restrict__ gnn_w, // [R]
    const float* __restrict__ gnn_b, // [1]
    float* __restrict__ coefQ,       // [N/4][N][4]
    float* __restrict__ deg)         // [N], pre-zeroed
{
    __shared__ float ct[64 * 68];
    const int t = threadIdx.x;
    const int it = blockIdx.x >> 4, jt = blockIdx.x & 15;
    const int i_loc = t >> 2, chunk = t & 3;
    float gw[5];
    #pragma unroll
    for (int f = 0; f < 5; ++f) gw[f] = gnn_w[f];
    const float gb = gnn_b[0];

    const float* Ab = A + ((size_t)(it * 64 + i_loc) * 1024 + jt * 64 + chunk * 16) * 5;
    float buf[80];
    #pragma unroll
    for (int k = 0; k < 20; ++k)
        *(float4*)&buf[4 * k] = ((const float4*)Ab)[k];

    float cnt = 0.f;
    #pragma unroll
    for (int jj = 0; jj < 16; ++jj) {
        float s = 0.f, d = gb;
        #pragma unroll
        for (int f = 0; f < 5; ++f) { float vv = buf[5 * jj + f]; s += vv; d = fmaf(vv, gw[f], d); }
        float cf = (s > 0.f) ? (d >= 0.f ? d : 0.2f * d) : 0.f;
        ct[i_loc * 68 + chunk * 16 + jj] = cf;
        cnt += (s > 0.f) ? 1.f : 0.f;
    }
    cnt += __shfl_xor(cnt, 1);
    cnt += __shfl_xor(cnt, 2);
    if ((t & 3) == 0) atomicAdd(&deg[it * 64 + i_loc], cnt);
    __syncthreads();

    const int i_o = t & 63;
    #pragma unroll
    for (int p = 0; p < 4; ++p) {
        int jg = (t >> 6) + 4 * p;
        float4 v = *(const float4*)&ct[i_o * 68 + 4 * jg];
        ((float4*)coefQ)[(size_t)(jt * 16 + jg) * 1024 + it * 64 + i_o] = v;
    }
}

// ---------------- Kernel 3: LDS-free MFMA GNN + prediction head -------------
// Block = (it 32-row i-tile, b); wave w covers j-tiles jt = 4w+s. ALL MFMA
// operands load directly from global as contiguous f16x8 (A-frags from E16
// rows, O-GEMM B-frags from ET rows) — no tile staging, no LDS buffers.
// Epilogue: per-wave partials -> 512 B LDS -> wave 0 writes final preds
// (no atomics, no preds memset).
__global__ __launch_bounds__(256, 3) void gnn_pred_kernel(
    const _Float16* __restrict__ E16,  // [B*N, H]
    const _Float16* __restrict__ ET,   // [B][H][N]
    const float* __restrict__ coefQ,   // [N/4][N][4]
    const float* __restrict__ deg,     // [N]
    const float* __restrict__ pred_w,  // [2H]
    const float* __restrict__ pred_b,  // [1]
    float* __restrict__ preds)         // [B*N]
{
    __shared__ float pacc[4][32];
    const int tid  = threadIdx.x;
    const int w    = tid >> 6;
    const int lane = tid & 63;
    const int l31  = lane & 31;
    const int hi   = lane >> 5;
    const int it   = blockIdx.x >> 5;           // 0..31 (32-row i-tile)
    const int b    = blockIdx.x & 31;

    const float4* coefQ4 = (const float4*)coefQ;

    // Ei B-fragments (B[k=h][n=i]), resident
    f16x8 eb[4];
    #pragma unroll
    for (int kt = 0; kt < 4; ++kt)
        eb[kt] = *(const f16x8*)(E16 +
            (size_t)(b * 1024 + it * 32 + l31) * 64 + kt * 16 + 8 * hi);

    f32x16 zero16 = {0,0,0,0,0,0,0,0,0,0,0,0,0,0,0,0};
    f32x16 oacc[2] = {zero16, zero16};

    #pragma unroll 1
    for (int s = 0; s < 4; ++s) {
        const int jt = 4 * w + s;
        #pragma unroll 1
        for (int mj = 0; mj < 2; ++mj) {
            // Ej A-frags (A[m=j][k=h]) straight from E16
            f16x8 afr[4];
            #pragma unroll
            for (int kt = 0; kt < 4; ++kt)
                afr[kt] = *(const f16x8*)(E16 +
                    (size_t)(b * 1024 + jt * 64 + mj * 32 + l31) * 64 + kt * 16 + 8 * hi);
            // S' = Ej . Ei^T
            f32x16 a = __builtin_amdgcn_mfma_f32_32x32x16_f16(afr[0], eb[0], zero16, 0, 0, 0);
            #pragma unroll
            for (int kt = 1; kt < 4; ++kt)
                a = __builtin_amdgcn_mfma_f32_32x32x16_f16(afr[kt], eb[kt], a, 0, 0, 0);
            // P = S' * coef (coalesced dwordx4 from coefQ)
            #pragma unroll
            for (int rg = 0; rg < 4; ++rg) {
                int j0 = jt * 64 + mj * 32 + 8 * rg + 4 * hi;
                float4 cf = coefQ4[(size_t)(j0 >> 2) * 1024 + it * 32 + l31];
                a[4 * rg + 0] *= cf.x; a[4 * rg + 1] *= cf.y;
                a[4 * rg + 2] *= cf.z; a[4 * rg + 3] *= cf.w;
            }
            // pack C-layout -> fp16 A-frags via lane^32 swap
            f16x8 pa[2];
            #pragma unroll
            for (int kk = 0; kk < 2; ++kk) {
                const int rg = 2 * kk;
                #pragma unroll
                for (int c4 = 0; c4 < 4; ++c4) {
                    float own_lo = a[rg * 4 + c4];
                    float own_hi = a[(rg + 1) * 4 + c4];
                    float send = hi ? own_lo : own_hi;
                    float recv = __shfl_xor(send, 32);
                    float lo = hi ? recv : own_lo;
                    float hv = hi ? own_hi : recv;
                    pa[kk][c4]     = (_Float16)lo;
                    pa[kk][4 + c4] = (_Float16)hv;
                }
            }
            // O += P . Ej  (B[k=j][n=h] straight from ET)
            #pragma unroll
            for (int nh = 0; nh < 2; ++nh)
                #pragma unroll
                for (int kk = 0; kk < 2; ++kk) {
                    const int ktj = 2 * mj + kk;
                    f16x8 bb = *(const f16x8*)(ET +
                        (size_t)(b * 64 + nh * 32 + l31) * 1024 +
                        jt * 64 + ktj * 16 + 8 * hi);
                    oacc[nh] = __builtin_amdgcn_mfma_f32_32x32x16_f16(
                        pa[kk], bb, oacc[nh], 0, 0, 0);
                }
        }
    }

    // ---- epilogue: per-wave O.pwh partials -> LDS; wave 0 finalizes -------
    const float pwh0 = pred_w[64 + l31];
    const float pwh1 = pred_w[96 + l31];
    #pragma unroll
    for (int r = 0; r < 16; ++r) {
        float v = oacc[0][r] * pwh0 + oacc[1][r] * pwh1;
        v += __shfl_xor(v, 1);  v += __shfl_xor(v, 2);  v += __shfl_xor(v, 4);
        v += __shfl_xor(v, 8);  v += __shfl_xor(v, 16);
        int i_loc = 8 * (r >> 2) + (r & 3) + 4 * hi;
        if (l31 == 0) pacc[w][i_loc] = v;
    }
    __syncthreads();
    if (w == 0) {
        float dot = 0.f;
        #pragma unroll
        for (int kt = 0; kt < 4; ++kt)
            #pragma unroll
            for (int e = 0; e < 8; ++e)
                dot = fmaf((float)eb[kt][e], pred_w[16 * kt + 8 * hi + e], dot);
        dot += __shfl_xor(dot, 32);
        if (hi == 0) {
            int gi = it * 32 + l31;
            float osum = pacc[0][l31] + pacc[1][l31] + pacc[2][l31] + pacc[3][l31];
            preds[b * 1024 + gi] = dot + osum * fast_rcp(deg[gi]) + pred_b[0];
        }
    }
}

extern "C" void kernel_launch(void* const* d_in, const int* in_sizes, int n_in,
                              void* d_out, int out_size, void* d_ws, size_t ws_size,
                              hipStream_t stream) {
    const float* x      = (const float*)d_in[0];
    const float* A      = (const float*)d_in[1];
    const float* Wih    = (const float*)d_in[2];
    const float* Whh    = (const float*)d_in[3];
    const float* bih    = (const float*)d_in[4];
    const float* bhh    = (const float*)d_in[5];
    const float* attn_w = (const float*)d_in[6];
    const float* attn_b = (const float*)d_in[7];
    const float* gnn_w  = (const float*)d_in[8];
    const float* gnn_b  = (const float*)d_in[9];
    const float* pred_w = (const float*)d_in[10];
    const float* pred_b = (const float*)d_in[11];
    float* preds = (float*)d_out;

    // ws: E16 (4MB) | ET (4MB) | coefQ (4MB) | deg (4KB)
    _Float16* E16 = (_Float16*)d_ws;
    _Float16* ET  = E16 + (size_t)BNc * Hc;
    float* coefQ  = (float*)(ET + (size_t)BNc * Hc);
    float* deg    = coefQ + (size_t)Nc * Nc;

    hipMemsetAsync(deg, 0, Nc * sizeof(float), stream);

    lstm_attn_kernel<<<BNc / 32, 256, 0, stream>>>(x, Wih, Whh, bih, bhh,
                                                   attn_w, attn_b, E16, ET);
    coefq_kernel<<<256, 256, 0, stream>>>(A, gnn_w, gnn_b, coefQ, deg);
    gnn_pred_kernel<<<Bc * (Nc / 32), 256, 0, stream>>>(E16, ET, coefQ, deg,
                                                        pred_w, pred_b, preds);
}

// Round 8
// 223.634 us; speedup vs baseline: 1.1328x; 1.1328x over previous
//
#include <hip/hip_runtime.h>

// Problem constants (B,N,T,F,H,R) = (32,1024,32,5,64,5)
constexpr int Bc = 32, Nc = 1024, Tc = 32, Fc = 5, Hc = 64;
constexpr int BNc = Bc * Nc;   // 32768 sequences

#define DEVFN __device__ __forceinline__

typedef _Float16 f16x8 __attribute__((ext_vector_type(8)));
typedef _Float16 f16x4 __attribute__((ext_vector_type(4)));
typedef float    f32x16 __attribute__((ext_vector_type(16)));

DEVFN float fast_rcp(float x) { return __builtin_amdgcn_rcpf(x); }
DEVFN float tanh_fast(float x) { return 1.f - 2.f * fast_rcp(__expf(2.f * x) + 1.f); }

// ---------------- Kernel 1: fused LSTM + temporal attention (MFMA) ----------
// R5 version (best measured: 123 µs): 2 waves x 32 seqs, wave owns 32 units,
// fused-denominator cell algebra (5 exp + 2 rcp per unit), pitch-64 swizzled
// fp16 h-exchange.
__global__ __launch_bounds__(128, 2) void lstm_attn_kernel(
    const float* __restrict__ x,      // [BN, T, F]
    const float* __restrict__ Wih,    // [4H, F]
    const float* __restrict__ Whh,    // [4H, H]
    const float* __restrict__ bih,    // [4H]
    const float* __restrict__ bhh,    // [4H]
    const float* __restrict__ attn_w, // [H]
    const float* __restrict__ attn_b, // [1]
    _Float16* __restrict__ E16,       // [B*N, H] fp16 row-major
    _Float16* __restrict__ ET)        // [B][H][N] fp16 transposed
{
    constexpr int XP = 164;                     // x pitch (halves)
    __shared__ __align__(16) _Float16 xs[32 * XP];   // 10.5 KB; aliased w/ es
    __shared__ __align__(16) _Float16 hb[2][32 * 64];// 8 KB h exchange
    __shared__ float ap[2][32];                 // attn partials per wave
    float* es = (float*)xs;                     // [32][65] epilogue bounce

    const int tid  = threadIdx.x;
    const int w    = tid >> 6;                  // wave id (0,1)
    const int lane = tid & 63;
    const int m    = lane & 31;                 // seq column
    const int hi   = lane >> 5;

    // ---- stage x (fp32 -> fp16 LDS) ----
    const float* xg = x + (size_t)blockIdx.x * 32 * Tc * Fc;
    for (int i = tid; i < 32 * 160; i += 128) {
        int mm = i / 160, o = i - mm * 160;
        xs[mm * XP + o] = (_Float16)xg[i];
    }
    // zero h buffer 0
    for (int i = tid; i < 1024; i += 128) ((uint*)&hb[0][0])[i] = 0u;

    // ---- preload A fragments: af[g][kt], jt = 2g+w, row j = 32*jt + m ----
    f16x8 af[4][5];
    #pragma unroll
    for (int g = 0; g < 4; ++g) {
        const int j = 32 * (2 * g + w) + m;     // = 64g + 32w + m
        #pragma unroll
        for (int kt = 0; kt < 4; ++kt) {
            const float* wp = Whh + j * 64 + kt * 16 + 8 * hi;
            float4 u0 = *(const float4*)wp;
            float4 u1 = *(const float4*)(wp + 4);
            af[g][kt] = f16x8{(_Float16)u0.x, (_Float16)u0.y, (_Float16)u0.z, (_Float16)u0.w,
                              (_Float16)u1.x, (_Float16)u1.y, (_Float16)u1.z, (_Float16)u1.w};
        }
        float v[8];
        #pragma unroll
        for (int e = 0; e < 5; ++e) v[e] = Wih[j * Fc + e];
        v[5] = bih[j] + bhh[j]; v[6] = 0.f; v[7] = 0.f;
        #pragma unroll
        for (int e = 0; e < 8; ++e) {
            float z = hi ? 0.f : v[e];
            af[g][4][e] = (_Float16)z;
        }
    }

    // attention weights for owned units u = 32w + 8a2 + 4hi + p
    float aw_own[16];
    #pragma unroll
    for (int a2 = 0; a2 < 4; ++a2)
        #pragma unroll
        for (int p = 0; p < 4; ++p)
            aw_own[a2 * 4 + p] = attn_w[32 * w + 8 * a2 + 4 * hi + p];
    const float ab = attn_b[0];

    float hcur[16], cst[16], oacc[16];
    #pragma unroll
    for (int i = 0; i < 16; ++i) { hcur[i] = 0.f; cst[i] = 0.f; oacc[i] = 0.f; }
    float lsum = 0.f;

    f32x16 zero16 = {0,0,0,0,0,0,0,0,0,0,0,0,0,0,0,0};
    const int xrow = m * XP;
    const int swz  = m & 15;                    // chunk XOR swizzle
    __syncthreads();

    // ---- initial B fragments from hb[0] (zeros) + x(0) ----
    f16x8 bf[5];
    #pragma unroll
    for (int kt = 0; kt < 4; ++kt) {
        f16x4 lo = *(const f16x4*)&hb[0][m * 64 + ((4 * kt + 2 * hi)     ^ swz) * 4];
        f16x4 hh = *(const f16x4*)&hb[0][m * 64 + ((4 * kt + 2 * hi + 1) ^ swz) * 4];
        bf[kt] = f16x8{lo[0], lo[1], lo[2], lo[3], hh[0], hh[1], hh[2], hh[3]};
    }
    {
        #pragma unroll
        for (int e = 0; e < 8; ++e) bf[4][e] = (_Float16)0.f;
        if (!hi) {
            #pragma unroll
            for (int e = 0; e < 5; ++e) bf[4][e] = xs[xrow + e];
            bf[4][5] = (_Float16)1.f;
        }
    }

    #pragma unroll 1
    for (int t = 0; t < Tc; ++t) {
        // ---- gates: 4 gate tiles x 5 k-tiles ----
        f32x16 acc[4];
        #pragma unroll
        for (int g = 0; g < 4; ++g) {
            acc[g] = __builtin_amdgcn_mfma_f32_32x32x16_f16(af[g][0], bf[0], zero16, 0, 0, 0);
            #pragma unroll
            for (int kt = 1; kt < 5; ++kt)
                acc[g] = __builtin_amdgcn_mfma_f32_32x32x16_f16(af[g][kt], bf[kt], acc[g], 0, 0, 0);
        }
        // ---- cell update: fused-denominator form, 5 exp + 2 rcp per unit ----
        float attnp = 0.f;
        #pragma unroll
        for (int r = 0; r < 16; ++r) {
            float ei = __expf(-acc[0][r]);          // e^{-i}
            float ef = __expf(-acc[1][r]);          // e^{-f}
            float Eg = __expf(2.f * acc[2][r]);     // e^{2g}
            float eo = __expf(-acc[3][r]);          // e^{-o}
            float u  = 1.f + ei;
            float v  = 1.f + ef;
            float wq = Eg + 1.f;
            float z  = Eg - 1.f;
            float t1 = u * wq;
            float num = fmaf(cst[r], t1, z * v);
            float cn = num * fast_rcp(t1 * v);
            cst[r] = cn;
            float E2 = __expf(2.f * cn);
            float hv = (E2 - 1.f) * fast_rcp((E2 + 1.f) * (1.f + eo));
            hcur[r] = hv;
            attnp = fmaf(hv, aw_own[r], attnp);
        }
        // ---- publish h (fp16, swizzled chunks) + attention partial ----
        _Float16* hw = &hb[(t + 1) & 1][0];
        #pragma unroll
        for (int a2 = 0; a2 < 4; ++a2) {
            f16x4 pk = {(_Float16)hcur[4 * a2 + 0], (_Float16)hcur[4 * a2 + 1],
                        (_Float16)hcur[4 * a2 + 2], (_Float16)hcur[4 * a2 + 3]};
            *(f16x4*)&hw[m * 64 + ((8 * w + 2 * a2 + hi) ^ swz) * 4] = pk;
        }
        attnp += __shfl_xor(attnp, 32);
        if (!hi) ap[w][m] = attnp;
        __syncthreads();
        // ---- score + online accumulation (both waves identical) ----
        float sc = tanh_fast(ap[0][m] + ap[1][m] + ab);
        float ew = __expf(sc);
        lsum += ew;
        #pragma unroll
        for (int i = 0; i < 16; ++i) oacc[i] = fmaf(ew, hcur[i], oacc[i]);
        // ---- build next B fragments ----
        if (t != Tc - 1) {
            const _Float16* hr = &hb[(t + 1) & 1][0];
            #pragma unroll
            for (int kt = 0; kt < 4; ++kt) {
                f16x4 lo = *(const f16x4*)&hr[m * 64 + ((4 * kt + 2 * hi)     ^ swz) * 4];
                f16x4 hh = *(const f16x4*)&hr[m * 64 + ((4 * kt + 2 * hi + 1) ^ swz) * 4];
                bf[kt] = f16x8{lo[0], lo[1], lo[2], lo[3], hh[0], hh[1], hh[2], hh[3]};
            }
            if (!hi) {
                #pragma unroll
                for (int e = 0; e < 5; ++e) bf[4][e] = xs[xrow + (t + 1) * Fc + e];
                bf[4][5] = (_Float16)1.f;
            }
        }
    }

    // ---- epilogue: es[m][u] = oacc/lsum, then E16 + ET ----
    __syncthreads();                    // xs reads done before aliasing
    const float li = fast_rcp(lsum);
    #pragma unroll
    for (int r = 0; r < 16; ++r) {
        int u = 32 * w + 8 * (r >> 2) + 4 * hi + (r & 3);
        es[m * 65 + u] = oacc[r] * li;
    }
    __syncthreads();

    uint* E16u = (uint*)E16 + (size_t)blockIdx.x * 32 * 32;
    for (int idx = tid; idx < 32 * 32; idx += 128) {
        int mm = idx >> 5, hp = idx & 31;
        union { _Float16 h2[2]; uint u; } cv;
        cv.h2[0] = (_Float16)es[mm * 65 + 2 * hp];
        cv.h2[1] = (_Float16)es[mm * 65 + 2 * hp + 1];
        E16u[idx] = cv.u;
    }
    const int bb_ = blockIdx.x >> 5, n0d = (blockIdx.x & 31) * 16;
    uint* ETu = (uint*)ET;
    for (int idx = tid; idx < 64 * 16; idx += 128) {
        int h = idx >> 4, c = idx & 15;
        union { _Float16 h2[2]; uint u; } cv;
        cv.h2[0] = (_Float16)es[(2 * c) * 65 + h];
        cv.h2[1] = (_Float16)es[(2 * c + 1) * 65 + h];
        ETu[((size_t)bb_ * 64 + h) * 512 + n0d + c] = cv.u;
    }
}

// ---------------- Kernel 2: edge coefficients, LDS-bounce version -----------
// Block = 32x32 edge tile (grid 1024). A staged via fully-coalesced float2
// loads into pitch-162 LDS (bank stride 2 -> 2-way aliasing = free), then
// per-thread j-quad compute; coefQ stores perfectly coalesced float4.
// Degree: per-(jt,i) partial counts to degP[32][1024] (no atomics, no memset).
__global__ __launch_bounds__(256, 4) void coefq_kernel(
    const float* __restrict__ A,     // [N, N, R]
    const float* __restrict__ gnn_w, // [R]
    const float* __restrict__ gnn_b, // [1]
    float* __restrict__ coefQ,       // [N/4][N][4]
    float* __restrict__ degP)        // [32][N] partial counts
{
    constexpr int CP = 162;                 // float pitch
    __shared__ float as[32 * CP];           // 20.7 KB
    __shared__ float dcnt[4][32];
    const int t  = threadIdx.x;
    const int it = blockIdx.x >> 5, jt = blockIdx.x & 31;

    float gw[5];
    #pragma unroll
    for (int f = 0; f < 5; ++f) gw[f] = gnn_w[f];
    const float gb = gnn_b[0];

    // ---- stage 32 rows x 160 floats (coalesced float2) ----
    const float* src = A + ((size_t)it * 32 * 1024 + jt * 32) * 5;
    #pragma unroll
    for (int k = 0; k < 10; ++k) {
        int idx = t + k * 256;              // 0..2559
        int row = idx / 80, c2 = idx - row * 80;
        *(float2*)&as[row * CP + c2 * 2] = *(const float2*)(src + (size_t)row * 5120 + c2 * 2);
    }
    __syncthreads();

    // ---- compute: thread (g = t>>5, i = t&31) handles j-quad g ----
    const int g = t >> 5, i_loc = t & 31;
    float cf[4]; float cnt = 0.f;
    #pragma unroll
    for (int q = 0; q < 4; ++q) {
        const float* ap = &as[i_loc * CP + (g * 4 + q) * 5];
        float s = 0.f, d = gb;
        #pragma unroll
        for (int f = 0; f < 5; ++f) { float vv = ap[f]; s += vv; d = fmaf(vv, gw[f], d); }
        cf[q] = (s > 0.f) ? (d >= 0.f ? d : 0.2f * d) : 0.f;
        cnt += (s > 0.f) ? 1.f : 0.f;
    }
    ((float4*)coefQ)[(size_t)(jt * 8 + g) * 1024 + it * 32 + i_loc] =
        float4{cf[0], cf[1], cf[2], cf[3]};

    // ---- degree partial: sum over the 8 g-groups for each i ----
    cnt += __shfl_xor(cnt, 32);             // combine g pairs within wave
    if ((t & 32) == 0) dcnt[t >> 6][i_loc] = cnt;
    __syncthreads();
    if (t < 32)
        degP[jt * 1024 + it * 32 + t] = dcnt[0][t] + dcnt[1][t] + dcnt[2][t] + dcnt[3][t];
}

// ---------------- Kernel 3: MFMA GNN message pass + prediction head ---------
// R6 structure (it-major, staged coalesced tiles, de-spilled) with atomic-free
// epilogue: per-wave partials into LDS (aliasing the dead EA tile), wave 0
// writes final preds directly (no preds memset, no global atomics).
__global__ __launch_bounds__(256, 2) void gnn_pred_kernel(
    const _Float16* __restrict__ E16,  // [B*N, H]
    const _Float16* __restrict__ ET,   // [B][H][N]
    const float* __restrict__ coefQ,   // [N/4][N][4]
    const float* __restrict__ degP,    // [32][N]
    const float* __restrict__ pred_w,  // [2H]
    const float* __restrict__ pred_b,  // [1]
    float* __restrict__ preds)         // [B*N]
{
    __shared__ __align__(16) _Float16 tiles[2][4][64 * 64];  // 64 KB exactly
    const int tid  = threadIdx.x;
    const int w    = tid >> 6;
    const int lane = tid & 63;
    const int l31  = lane & 31;
    const int hi   = lane >> 5;
    const int it   = blockIdx.x >> 5;           // it-major (XCD locality)
    const int b    = blockIdx.x & 31;

    _Float16* EA = &tiles[0][w][0];
    _Float16* EB = &tiles[1][w][0];
    const float4* coefQ4 = (const float4*)coefQ;

    f16x8 eb[2][4];
    #pragma unroll
    for (int ni = 0; ni < 2; ++ni)
        #pragma unroll
        for (int kt = 0; kt < 4; ++kt)
            eb[ni][kt] = *(const f16x8*)(E16 +
                ((size_t)(b * 1024 + it * 64 + ni * 32 + l31) * 64 + 16 * kt + 8 * hi));

    f32x16 zero16 = {0,0,0,0,0,0,0,0,0,0,0,0,0,0,0,0};
    f32x16 oacc[2][2];
    #pragma unroll
    for (int mi = 0; mi < 2; ++mi)
        #pragma unroll
        for (int nh = 0; nh < 2; ++nh) oacc[mi][nh] = zero16;

    #pragma unroll 1
    for (int s = 0; s < 4; ++s) {
        const int jt = w * 4 + s;
        const _Float16* srcA = E16 + (size_t)(b * 1024 + jt * 64) * 64;
        const _Float16* srcB = ET + (size_t)b * 64 * 1024 + jt * 64;
        #pragma unroll
        for (int q = 0; q < 8; ++q) {
            int f = q * 64 + lane, r = f >> 3, c = f & 7;
            uint4 va = *(const uint4*)(srcA + r * 64 + c * 8);
            *(uint4*)(EA + r * 64 + ((c ^ (r & 7)) * 8)) = va;
            uint4 vb = *(const uint4*)(srcB + r * 1024 + c * 8);
            *(uint4*)(EB + r * 64 + ((c ^ (r & 7)) * 8)) = vb;
        }
        #pragma unroll 1
        for (int mj = 0; mj < 2; ++mj) {
            f16x8 af[4];
            #pragma unroll
            for (int kt = 0; kt < 4; ++kt)
                af[kt] = *(const f16x8*)(EA + (mj * 32 + l31) * 64 +
                                         (((2 * kt + hi) ^ (l31 & 7)) * 8));
            #pragma unroll
            for (int mi = 0; mi < 2; ++mi) {
                // S' = Ej . Ei^T  (16 regs live)
                f32x16 a = __builtin_amdgcn_mfma_f32_32x32x16_f16(af[0], eb[mi][0], zero16, 0, 0, 0);
                #pragma unroll
                for (int kt = 1; kt < 4; ++kt)
                    a = __builtin_amdgcn_mfma_f32_32x32x16_f16(af[kt], eb[mi][kt], a, 0, 0, 0);
                // P = S' * coef
                #pragma unroll
                for (int rg = 0; rg < 4; ++rg) {
                    int j0 = jt * 64 + mj * 32 + 8 * rg + 4 * hi;
                    float4 cf = coefQ4[(size_t)(j0 >> 2) * 1024 + it * 64 + mi * 32 + l31];
                    a[4 * rg + 0] *= cf.x; a[4 * rg + 1] *= cf.y;
                    a[4 * rg + 2] *= cf.z; a[4 * rg + 3] *= cf.w;
                }
                // pack C-layout -> fp16 A-frags via lane^32 swap
                f16x8 pa[2];
                #pragma unroll
                for (int kk = 0; kk < 2; ++kk) {
                    const int rg = 2 * kk;
                    #pragma unroll
                    for (int c4 = 0; c4 < 4; ++c4) {
                        float own_lo = a[rg * 4 + c4];
                        float own_hi = a[(rg + 1) * 4 + c4];
                        float send = hi ? own_lo : own_hi;
                        float recv = __shfl_xor(send, 32);
                        float lo = hi ? recv : own_lo;
                        float hv = hi ? own_hi : recv;
                        pa[kk][c4]     = (_Float16)lo;
                        pa[kk][4 + c4] = (_Float16)hv;
                    }
                }
                // O += P . Ej
                #pragma unroll
                for (int nh = 0; nh < 2; ++nh)
                    #pragma unroll
                    for (int kk = 0; kk < 2; ++kk) {
                        const int ktj = 2 * mj + kk;
                        f16x8 bb = *(const f16x8*)(EB + (nh * 32 + l31) * 64 +
                                                   (((2 * ktj + hi) ^ (l31 & 7)) * 8));
                        oacc[mi][nh] = __builtin_amdgcn_mfma_f32_32x32x16_f16(
                            pa[kk], bb, oacc[mi][nh], 0, 0, 0);
                    }
            }
        }
    }

    // ---- epilogue: per-wave O.pwh partials -> LDS (aliases dead EA tile) ---
    float* pacc = (float*)&tiles[0][w][0];      // 64 floats, wave-private
    const float pwh0 = pred_w[64 + l31];
    const float pwh1 = pred_w[96 + l31];
    #pragma unroll
    for (int mi = 0; mi < 2; ++mi)
        #pragma unroll
        for (int r = 0; r < 16; ++r) {
            float v = oacc[mi][0][r] * pwh0 + oacc[mi][1][r] * pwh1;
            v += __shfl_xor(v, 1);  v += __shfl_xor(v, 2);  v += __shfl_xor(v, 4);
            v += __shfl_xor(v, 8);  v += __shfl_xor(v, 16);
            int i_loc = mi * 32 + 8 * (r >> 2) + (r & 3) + 4 * hi;
            if (l31 == 0) pacc[i_loc] = v;
        }
    __syncthreads();
    if (w == 0) {
        const float pb0 = pred_b[0];
        #pragma unroll
        for (int ni = 0; ni < 2; ++ni) {
            float dot = 0.f;
            #pragma unroll
            for (int kt = 0; kt < 4; ++kt)
                #pragma unroll
                for (int e = 0; e < 8; ++e)
                    dot = fmaf((float)eb[ni][kt][e], pred_w[16 * kt + 8 * hi + e], dot);
            dot += __shfl_xor(dot, 32);
            if (hi == 0) {
                int i_loc = ni * 32 + l31;
                int gi = it * 64 + i_loc;
                float osum = ((float*)&tiles[0][0][0])[i_loc] +
                             ((float*)&tiles[0][1][0])[i_loc] +
                             ((float*)&tiles[0][2][0])[i_loc] +
                             ((float*)&tiles[0][3][0])[i_loc];
                float dsum = 0.f;
                #pragma unroll
                for (int jj = 0; jj < 32; ++jj) dsum += degP[jj * 1024 + gi];
                preds[b * 1024 + gi] = dot + osum * fast_rcp(dsum) + pb0;
            }
        }
    }
}

extern "C" void kernel_launch(void* const* d_in, const int* in_sizes, int n_in,
                              void* d_out, int out_size, void* d_ws, size_t ws_size,
                              hipStream_t stream) {
    const float* x      = (const float*)d_in[0];
    const float* A      = (const float*)d_in[1];
    const float* Wih    = (const float*)d_in[2];
    const float* Whh    = (const float*)d_in[3];
    const float* bih    = (const float*)d_in[4];
    const float* bhh    = (const float*)d_in[5];
    const float* attn_w = (const float*)d_in[6];
    const float* attn_b = (const float*)d_in[7];
    const float* gnn_w  = (const float*)d_in[8];
    const float* gnn_b  = (const float*)d_in[9];
    const float* pred_w = (const float*)d_in[10];
    const float* pred_b = (const float*)d_in[11];
    float* preds = (float*)d_out;

    // ws: E16 (4MB) | ET (4MB) | coefQ (4MB) | degP (128KB)
    _Float16* E16 = (_Float16*)d_ws;
    _Float16* ET  = E16 + (size_t)BNc * Hc;
    float* coefQ  = (float*)(ET + (size_t)BNc * Hc);
    float* degP   = coefQ + (size_t)Nc * Nc;

    lstm_attn_kernel<<<BNc / 32, 128, 0, stream>>>(x, Wih, Whh, bih, bhh,
                                                   attn_w, attn_b, E16, ET);
    coefq_kernel<<<1024, 256, 0, stream>>>(A, gnn_w, gnn_b, coefQ, degP);
    gnn_pred_kernel<<<Bc * (Nc / 64), 256, 0, stream>>>(E16, ET, coefQ, degP,
                                                        pred_w, pred_b, preds);
}

// Round 9
// 221.965 us; speedup vs baseline: 1.1413x; 1.0075x over previous
//
#include <hip/hip_runtime.h>

// Problem constants (B,N,T,F,H,R) = (32,1024,32,5,64,5)
constexpr int Bc = 32, Nc = 1024, Tc = 32, Fc = 5, Hc = 64;
constexpr int BNc = Bc * Nc;   // 32768 sequences

#define DEVFN __device__ __forceinline__

typedef _Float16 f16x8 __attribute__((ext_vector_type(8)));
typedef _Float16 f16x4 __attribute__((ext_vector_type(4)));
typedef float    f32x16 __attribute__((ext_vector_type(16)));

DEVFN float fast_rcp(float x) { return __builtin_amdgcn_rcpf(x); }
DEVFN float tanh_fast(float x) { return 1.f - 2.f * fast_rcp(__expf(2.f * x) + 1.f); }

#if __has_builtin(__builtin_amdgcn_exp2f)
DEVFN float exp2_fast(float x) { return __builtin_amdgcn_exp2f(x); }
#else
DEVFN float exp2_fast(float x) { return exp2f(x); }
#endif

// ---------------- Kernel 1: fused LSTM + temporal attention (MFMA) ----------
// R5 structure (best measured): 2 waves x 32 seqs, wave owns 32 units,
// fused-denominator cell algebra, pitch-64 swizzled fp16 h-exchange.
// NEW: exp2 weight folding — gate rows pre-scaled by {-log2e, -log2e,
// +2log2e, -log2e} so the cell update uses raw v_exp_f32 (2^x) with no
// per-call multiply:  ei=2^acc0=e^{-i}, Eg=2^acc2=e^{2g}, etc.
__global__ __launch_bounds__(128, 2) void lstm_attn_kernel(
    const float* __restrict__ x,      // [BN, T, F]
    const float* __restrict__ Wih,    // [4H, F]
    const float* __restrict__ Whh,    // [4H, H]
    const float* __restrict__ bih,    // [4H]
    const float* __restrict__ bhh,    // [4H]
    const float* __restrict__ attn_w, // [H]
    const float* __restrict__ attn_b, // [1]
    _Float16* __restrict__ E16,       // [B*N, H] fp16 row-major
    _Float16* __restrict__ ET)        // [B][H][N] fp16 transposed
{
    constexpr int XP = 164;                     // x pitch (halves)
    __shared__ __align__(16) _Float16 xs[32 * XP];   // 10.5 KB; aliased w/ es
    __shared__ __align__(16) _Float16 hb[2][32 * 64];// 8 KB h exchange
    __shared__ float ap[2][32];                 // attn partials per wave
    float* es = (float*)xs;                     // [32][65] epilogue bounce

    const int tid  = threadIdx.x;
    const int w    = tid >> 6;                  // wave id (0,1)
    const int lane = tid & 63;
    const int m    = lane & 31;                 // seq column
    const int hi   = lane >> 5;

    // ---- stage x (fp32 -> fp16 LDS) ----
    const float* xg = x + (size_t)blockIdx.x * 32 * Tc * Fc;
    for (int i = tid; i < 32 * 160; i += 128) {
        int mm = i / 160, o = i - mm * 160;
        xs[mm * XP + o] = (_Float16)xg[i];
    }
    // zero h buffer 0
    for (int i = tid; i < 1024; i += 128) ((uint*)&hb[0][0])[i] = 0u;

    // per-gate exp2 folding scales (gate order i,f,g,o)
    constexpr float L2E = 1.4426950408889634f;
    const float gsc[4] = {-L2E, -L2E, 2.f * L2E, -L2E};

    // ---- preload A fragments: af[g][kt], jt = 2g+w, row j = 32*jt + m ----
    f16x8 af[4][5];
    #pragma unroll
    for (int g = 0; g < 4; ++g) {
        const int j = 32 * (2 * g + w) + m;     // = 64g + 32w + m
        const float sc = gsc[g];
        #pragma unroll
        for (int kt = 0; kt < 4; ++kt) {
            const float* wp = Whh + j * 64 + kt * 16 + 8 * hi;
            float4 u0 = *(const float4*)wp;
            float4 u1 = *(const float4*)(wp + 4);
            af[g][kt] = f16x8{(_Float16)(sc * u0.x), (_Float16)(sc * u0.y),
                              (_Float16)(sc * u0.z), (_Float16)(sc * u0.w),
                              (_Float16)(sc * u1.x), (_Float16)(sc * u1.y),
                              (_Float16)(sc * u1.z), (_Float16)(sc * u1.w)};
        }
        float v[8];
        #pragma unroll
        for (int e = 0; e < 5; ++e) v[e] = sc * Wih[j * Fc + e];
        v[5] = sc * (bih[j] + bhh[j]); v[6] = 0.f; v[7] = 0.f;
        #pragma unroll
        for (int e = 0; e < 8; ++e) {
            float z = hi ? 0.f : v[e];
            af[g][4][e] = (_Float16)z;
        }
    }

    // attention weights for owned units u = 32w + 8a2 + 4hi + p
    float aw_own[16];
    #pragma unroll
    for (int a2 = 0; a2 < 4; ++a2)
        #pragma unroll
        for (int p = 0; p < 4; ++p)
            aw_own[a2 * 4 + p] = attn_w[32 * w + 8 * a2 + 4 * hi + p];
    const float ab = attn_b[0];

    float hcur[16], cst[16], oacc[16];
    #pragma unroll
    for (int i = 0; i < 16; ++i) { hcur[i] = 0.f; cst[i] = 0.f; oacc[i] = 0.f; }
    float lsum = 0.f;

    f32x16 zero16 = {0,0,0,0,0,0,0,0,0,0,0,0,0,0,0,0};
    const int xrow = m * XP;
    const int swz  = m & 15;                    // chunk XOR swizzle
    __syncthreads();

    // ---- initial B fragments from hb[0] (zeros) + x(0) ----
    f16x8 bf[5];
    #pragma unroll
    for (int kt = 0; kt < 4; ++kt) {
        f16x4 lo = *(const f16x4*)&hb[0][m * 64 + ((4 * kt + 2 * hi)     ^ swz) * 4];
        f16x4 hh = *(const f16x4*)&hb[0][m * 64 + ((4 * kt + 2 * hi + 1) ^ swz) * 4];
        bf[kt] = f16x8{lo[0], lo[1], lo[2], lo[3], hh[0], hh[1], hh[2], hh[3]};
    }
    {
        #pragma unroll
        for (int e = 0; e < 8; ++e) bf[4][e] = (_Float16)0.f;
        if (!hi) {
            #pragma unroll
            for (int e = 0; e < 5; ++e) bf[4][e] = xs[xrow + e];
            bf[4][5] = (_Float16)1.f;
        }
    }

    #pragma unroll 1
    for (int t = 0; t < Tc; ++t) {
        // ---- gates: 4 gate tiles x 5 k-tiles ----
        f32x16 acc[4];
        #pragma unroll
        for (int g = 0; g < 4; ++g) {
            acc[g] = __builtin_amdgcn_mfma_f32_32x32x16_f16(af[g][0], bf[0], zero16, 0, 0, 0);
            #pragma unroll
            for (int kt = 1; kt < 5; ++kt)
                acc[g] = __builtin_amdgcn_mfma_f32_32x32x16_f16(af[g][kt], bf[kt], acc[g], 0, 0, 0);
        }
        // ---- cell update: 5 exp2 + 2 rcp per unit (weights pre-scaled) ----
        float attnp = 0.f;
        #pragma unroll
        for (int r = 0; r < 16; ++r) {
            float ei = exp2_fast(acc[0][r]);        // e^{-i}
            float ef = exp2_fast(acc[1][r]);        // e^{-f}
            float Eg = exp2_fast(acc[2][r]);        // e^{2g}
            float eo = exp2_fast(acc[3][r]);        // e^{-o}
            float u  = 1.f + ei;
            float v  = 1.f + ef;
            float wq = Eg + 1.f;
            float z  = Eg - 1.f;
            float t1 = u * wq;
            float num = fmaf(cst[r], t1, z * v);
            float cn = num * fast_rcp(t1 * v);
            cst[r] = cn;
            float E2 = exp2_fast(2.f * L2E * cn);   // e^{2c}
            float hv = (E2 - 1.f) * fast_rcp((E2 + 1.f) * (1.f + eo));
            hcur[r] = hv;
            attnp = fmaf(hv, aw_own[r], attnp);
        }
        // ---- publish h (fp16, swizzled chunks) + attention partial ----
        _Float16* hw = &hb[(t + 1) & 1][0];
        #pragma unroll
        for (int a2 = 0; a2 < 4; ++a2) {
            f16x4 pk = {(_Float16)hcur[4 * a2 + 0], (_Float16)hcur[4 * a2 + 1],
                        (_Float16)hcur[4 * a2 + 2], (_Float16)hcur[4 * a2 + 3]};
            *(f16x4*)&hw[m * 64 + ((8 * w + 2 * a2 + hi) ^ swz) * 4] = pk;
        }
        attnp += __shfl_xor(attnp, 32);
        if (!hi) ap[w][m] = attnp;
        __syncthreads();
        // ---- score + online accumulation (both waves identical) ----
        float sc = tanh_fast(ap[0][m] + ap[1][m] + ab);
        float ew = __expf(sc);
        lsum += ew;
        #pragma unroll
        for (int i = 0; i < 16; ++i) oacc[i] = fmaf(ew, hcur[i], oacc[i]);
        // ---- build next B fragments ----
        if (t != Tc - 1) {
            const _Float16* hr = &hb[(t + 1) & 1][0];
            #pragma unroll
            for (int kt = 0; kt < 4; ++kt) {
                f16x4 lo = *(const f16x4*)&hr[m * 64 + ((4 * kt + 2 * hi)     ^ swz) * 4];
                f16x4 hh = *(const f16x4*)&hr[m * 64 + ((4 * kt + 2 * hi + 1) ^ swz) * 4];
                bf[kt] = f16x8{lo[0], lo[1], lo[2], lo[3], hh[0], hh[1], hh[2], hh[3]};
            }
            if (!hi) {
                #pragma unroll
                for (int e = 0; e < 5; ++e) bf[4][e] = xs[xrow + (t + 1) * Fc + e];
                bf[4][5] = (_Float16)1.f;
            }
        }
    }

    // ---- epilogue: es[m][u] = oacc/lsum, then E16 + ET ----
    __syncthreads();                    // xs reads done before aliasing
    const float li = fast_rcp(lsum);
    #pragma unroll
    for (int r = 0; r < 16; ++r) {
        int u = 32 * w + 8 * (r >> 2) + 4 * hi + (r & 3);
        es[m * 65 + u] = oacc[r] * li;
    }
    __syncthreads();

    uint* E16u = (uint*)E16 + (size_t)blockIdx.x * 32 * 32;
    for (int idx = tid; idx < 32 * 32; idx += 128) {
        int mm = idx >> 5, hp = idx & 31;
        union { _Float16 h2[2]; uint u; } cv;
        cv.h2[0] = (_Float16)es[mm * 65 + 2 * hp];
        cv.h2[1] = (_Float16)es[mm * 65 + 2 * hp + 1];
        E16u[idx] = cv.u;
    }
    const int bb_ = blockIdx.x >> 5, n0d = (blockIdx.x & 31) * 16;
    uint* ETu = (uint*)ET;
    for (int idx = tid; idx < 64 * 16; idx += 128) {
        int h = idx >> 4, c = idx & 15;
        union { _Float16 h2[2]; uint u; } cv;
        cv.h2[0] = (_Float16)es[(2 * c) * 65 + h];
        cv.h2[1] = (_Float16)es[(2 * c + 1) * 65 + h];
        ETu[((size_t)bb_ * 64 + h) * 512 + n0d + c] = cv.u;
    }
}

// ---------------- Kernel 2: edge coefficients, LDS-bounce version -----------
__global__ __launch_bounds__(256, 4) void coefq_kernel(
    const float* __restrict__ A,     // [N, N, R]
    const float* __restrict__ gnn_w, // [R]
    const float* __restrict__ gnn_b, // [1]
    float* __restrict__ coefQ,       // [N/4][N][4]
    float* __restrict__ degP)        // [32][N] partial counts
{
    constexpr int CP = 162;                 // float pitch
    __shared__ float as[32 * CP];           // 20.7 KB
    __shared__ float dcnt[4][32];
    const int t  = threadIdx.x;
    const int it = blockIdx.x >> 5, jt = blockIdx.x & 31;

    float gw[5];
    #pragma unroll
    for (int f = 0; f < 5; ++f) gw[f] = gnn_w[f];
    const float gb = gnn_b[0];

    // ---- stage 32 rows x 160 floats (coalesced float2) ----
    const float* src = A + ((size_t)it * 32 * 1024 + jt * 32) * 5;
    #pragma unroll
    for (int k = 0; k < 10; ++k) {
        int idx = t + k * 256;              // 0..2559
        int row = idx / 80, c2 = idx - row * 80;
        *(float2*)&as[row * CP + c2 * 2] = *(const float2*)(src + (size_t)row * 5120 + c2 * 2);
    }
    __syncthreads();

    // ---- compute: thread (g = t>>5, i = t&31) handles j-quad g ----
    const int g = t >> 5, i_loc = t & 31;
    float cf[4]; float cnt = 0.f;
    #pragma unroll
    for (int q = 0; q < 4; ++q) {
        const float* ap = &as[i_loc * CP + (g * 4 + q) * 5];
        float s = 0.f, d = gb;
        #pragma unroll
        for (int f = 0; f < 5; ++f) { float vv = ap[f]; s += vv; d = fmaf(vv, gw[f], d); }
        cf[q] = (s > 0.f) ? (d >= 0.f ? d : 0.2f * d) : 0.f;
        cnt += (s > 0.f) ? 1.f : 0.f;
    }
    ((float4*)coefQ)[(size_t)(jt * 8 + g) * 1024 + it * 32 + i_loc] =
        float4{cf[0], cf[1], cf[2], cf[3]};

    // ---- degree partial: sum over the 8 g-groups for each i ----
    cnt += __shfl_xor(cnt, 32);             // combine g pairs within wave
    if ((t & 32) == 0) dcnt[t >> 6][i_loc] = cnt;
    __syncthreads();
    if (t < 32)
        degP[jt * 1024 + it * 32 + t] = dcnt[0][t] + dcnt[1][t] + dcnt[2][t] + dcnt[3][t];
}

// ---------------- Kernel 3: MFMA GNN message pass + prediction head ---------
__global__ __launch_bounds__(256, 2) void gnn_pred_kernel(
    const _Float16* __restrict__ E16,  // [B*N, H]
    const _Float16* __restrict__ ET,   // [B][H][N]
    const float* __restrict__ coefQ,   // [N/4][N][4]
    const float* __restrict__ degP,    // [32][N]
    const float* __restrict__ pred_w,  // [2H]
    const float* __restrict__ pred_b,  // [1]
    float* __restrict__ preds)         // [B*N]
{
    __shared__ __align__(16) _Float16 tiles[2][4][64 * 64];  // 64 KB exactly
    const int tid  = threadIdx.x;
    const int w    = tid >> 6;
    const int lane = tid & 63;
    const int l31  = lane & 31;
    const int hi   = lane >> 5;
    const int it   = blockIdx.x >> 5;           // it-major (XCD locality)
    const int b    = blockIdx.x & 31;

    _Float16* EA = &tiles[0][w][0];
    _Float16* EB = &tiles[1][w][0];
    const float4* coefQ4 = (const float4*)coefQ;

    f16x8 eb[2][4];
    #pragma unroll
    for (int ni = 0; ni < 2; ++ni)
        #pragma unroll
        for (int kt = 0; kt < 4; ++kt)
            eb[ni][kt] = *(const f16x8*)(E16 +
                ((size_t)(b * 1024 + it * 64 + ni * 32 + l31) * 64 + 16 * kt + 8 * hi));

    f32x16 zero16 = {0,0,0,0,0,0,0,0,0,0,0,0,0,0,0,0};
    f32x16 oacc[2][2];
    #pragma unroll
    for (int mi = 0; mi < 2; ++mi)
        #pragma unroll
        for (int nh = 0; nh < 2; ++nh) oacc[mi][nh] = zero16;

    #pragma unroll 1
    for (int s = 0; s < 4; ++s) {
        const int jt = w * 4 + s;
        const _Float16* srcA = E16 + (size_t)(b * 1024 + jt * 64) * 64;
        const _Float16* srcB = ET + (size_t)b * 64 * 1024 + jt * 64;
        #pragma unroll
        for (int q = 0; q < 8; ++q) {
            int f = q * 64 + lane, r = f >> 3, c = f & 7;
            uint4 va = *(const uint4*)(srcA + r * 64 + c * 8);
            *(uint4*)(EA + r * 64 + ((c ^ (r & 7)) * 8)) = va;
            uint4 vb = *(const uint4*)(srcB + r * 1024 + c * 8);
            *(uint4*)(EB + r * 64 + ((c ^ (r & 7)) * 8)) = vb;
        }
        #pragma unroll 1
        for (int mj = 0; mj < 2; ++mj) {
            f16x8 af[4];
            #pragma unroll
            for (int kt = 0; kt < 4; ++kt)
                af[kt] = *(const f16x8*)(EA + (mj * 32 + l31) * 64 +
                                         (((2 * kt + hi) ^ (l31 & 7)) * 8));
            #pragma unroll
            for (int mi = 0; mi < 2; ++mi) {
                // S' = Ej . Ei^T  (16 regs live)
                f32x16 a = __builtin_amdgcn_mfma_f32_32x32x16_f16(af[0], eb[mi][0], zero16, 0, 0, 0);
                #pragma unroll
                for (int kt = 1; kt < 4; ++kt)
                    a = __builtin_amdgcn_mfma_f32_32x32x16_f16(af[kt], eb[mi][kt], a, 0, 0, 0);
                // P = S' * coef
                #pragma unroll
                for (int rg = 0; rg < 4; ++rg) {
                    int j0 = jt * 64 + mj * 32 + 8 * rg + 4 * hi;
                    float4 cf = coefQ4[(size_t)(j0 >> 2) * 1024 + it * 64 + mi * 32 + l31];
                    a[4 * rg + 0] *= cf.x; a[4 * rg + 1] *= cf.y;
                    a[4 * rg + 2] *= cf.z; a[4 * rg + 3] *= cf.w;
                }
                // pack C-layout -> fp16 A-frags via lane^32 swap
                f16x8 pa[2];
                #pragma unroll
                for (int kk = 0; kk < 2; ++kk) {
                    const int rg = 2 * kk;
                    #pragma unroll
                    for (int c4 = 0; c4 < 4; ++c4) {
                        float own_lo = a[rg * 4 + c4];
                        float own_hi = a[(rg + 1) * 4 + c4];
                        float send = hi ? own_lo : own_hi;
                        float recv = __shfl_xor(send, 32);
                        float lo = hi ? recv : own_lo;
                        float hv = hi ? own_hi : recv;
                        pa[kk][c4]     = (_Float16)lo;
                        pa[kk][4 + c4] = (_Float16)hv;
                    }
                }
                // O += P . Ej
                #pragma unroll
                for (int nh = 0; nh < 2; ++nh)
                    #pragma unroll
                    for (int kk = 0; kk < 2; ++kk) {
                        const int ktj = 2 * mj + kk;
                        f16x8 bb = *(const f16x8*)(EB + (nh * 32 + l31) * 64 +
                                                   (((2 * ktj + hi) ^ (l31 & 7)) * 8));
                        oacc[mi][nh] = __builtin_amdgcn_mfma_f32_32x32x16_f16(
                            pa[kk], bb, oacc[mi][nh], 0, 0, 0);
                    }
            }
        }
    }

    // ---- epilogue: per-wave O.pwh partials -> LDS (aliases dead EA tile) ---
    float* pacc = (float*)&tiles[0][w][0];      // 64 floats, wave-private
    const float pwh0 = pred_w[64 + l31];
    const float pwh1 = pred_w[96 + l31];
    #pragma unroll
    for (int mi = 0; mi < 2; ++mi)
        #pragma unroll
        for (int r = 0; r < 16; ++r) {
            float v = oacc[mi][0][r] * pwh0 + oacc[mi][1][r] * pwh1;
            v += __shfl_xor(v, 1);  v += __shfl_xor(v, 2);  v += __shfl_xor(v, 4);
            v += __shfl_xor(v, 8);  v += __shfl_xor(v, 16);
            int i_loc = mi * 32 + 8 * (r >> 2) + (r & 3) + 4 * hi;
            if (l31 == 0) pacc[i_loc] = v;
        }
    __syncthreads();
    if (w == 0) {
        const float pb0 = pred_b[0];
        #pragma unroll
        for (int ni = 0; ni < 2; ++ni) {
            float dot = 0.f;
            #pragma unroll
            for (int kt = 0; kt < 4; ++kt)
                #pragma unroll
                for (int e = 0; e < 8; ++e)
                    dot = fmaf((float)eb[ni][kt][e], pred_w[16 * kt + 8 * hi + e], dot);
            dot += __shfl_xor(dot, 32);
            if (hi == 0) {
                int i_loc = ni * 32 + l31;
                int gi = it * 64 + i_loc;
                float osum = ((float*)&tiles[0][0][0])[i_loc] +
                             ((float*)&tiles[0][1][0])[i_loc] +
                             ((float*)&tiles[0][2][0])[i_loc] +
                             ((float*)&tiles[0][3][0])[i_loc];
                float dsum = 0.f;
                #pragma unroll
                for (int jj = 0; jj < 32; ++jj) dsum += degP[jj * 1024 + gi];
                preds[b * 1024 + gi] = dot + osum * fast_rcp(dsum) + pb0;
            }
        }
    }
}

extern "C" void kernel_launch(void* const* d_in, const int* in_sizes, int n_in,
                              void* d_out, int out_size, void* d_ws, size_t ws_size,
                              hipStream_t stream) {
    const float* x      = (const float*)d_in[0];
    const float* A      = (const float*)d_in[1];
    const float* Wih    = (const float*)d_in[2];
    const float* Whh    = (const float*)d_in[3];
    const float* bih    = (const float*)d_in[4];
    const float* bhh    = (const float*)d_in[5];
    const float* attn_w = (const float*)d_in[6];
    const float* attn_b = (const float*)d_in[7];
    const float* gnn_w  = (const float*)d_in[8];
    const float* gnn_b  = (const float*)d_in[9];
    const float* pred_w = (const float*)d_in[10];
    const float* pred_b = (const float*)d_in[11];
    float* preds = (float*)d_out;

    // ws: E16 (4MB) | ET (4MB) | coefQ (4MB) | degP (128KB)
    _Float16* E16 = (_Float16*)d_ws;
    _Float16* ET  = E16 + (size_t)BNc * Hc;
    float* coefQ  = (float*)(ET + (size_t)BNc * Hc);
    float* degP   = coefQ + (size_t)Nc * Nc;

    lstm_attn_kernel<<<BNc / 32, 128, 0, stream>>>(x, Wih, Whh, bih, bhh,
                                                   attn_w, attn_b, E16, ET);
    coefq_kernel<<<1024, 256, 0, stream>>>(A, gnn_w, gnn_b, coefQ, degP);
    gnn_pred_kernel<<<Bc * (Nc / 64), 256, 0, stream>>>(E16, ET, coefQ, degP,
                                                        pred_w, pred_b, preds);
}

// Round 10
// 218.535 us; speedup vs baseline: 1.1592x; 1.0157x over previous
//
#include <hip/hip_runtime.h>

// Problem constants (B,N,T,F,H,R) = (32,1024,32,5,64,5)
constexpr int Bc = 32, Nc = 1024, Tc = 32, Fc = 5, Hc = 64;
constexpr int BNc = Bc * Nc;   // 32768 sequences

#define DEVFN __device__ __forceinline__

typedef _Float16 f16x8 __attribute__((ext_vector_type(8)));
typedef _Float16 f16x4 __attribute__((ext_vector_type(4)));
typedef float    f32x16 __attribute__((ext_vector_type(16)));

DEVFN float fast_rcp(float x) { return __builtin_amdgcn_rcpf(x); }
DEVFN float tanh_fast(float x) { return 1.f - 2.f * fast_rcp(__expf(2.f * x) + 1.f); }

#if __has_builtin(__builtin_amdgcn_exp2f)
DEVFN float exp2_fast(float x) { return __builtin_amdgcn_exp2f(x); }
#else
DEVFN float exp2_fast(float x) { return exp2f(x); }
#endif

// ---------------- Kernel 1: fused LSTM + temporal attention (MFMA) ----------
// 2 waves x 32 seqs; wave w owns units [32w,32w+32). exp2-folded weights.
// R10: (a) per-gate 16-reg accumulator -> exp2'd immediately into plain VGPRs
// (shrinks the long-lived MFMA destination 64->16 regs; avoids AGPR
// round-trips), (b) f32 h-exchange (publish = raw float4 stores, zero cvt;
// fp16 quantization happens once at the MFMA operand, numerics unchanged).
__global__ __launch_bounds__(128, 2) void lstm_attn_kernel(
    const float* __restrict__ x,      // [BN, T, F]
    const float* __restrict__ Wih,    // [4H, F]
    const float* __restrict__ Whh,    // [4H, H]
    const float* __restrict__ bih,    // [4H]
    const float* __restrict__ bhh,    // [4H]
    const float* __restrict__ attn_w, // [H]
    const float* __restrict__ attn_b, // [1]
    _Float16* __restrict__ E16,       // [B*N, H] fp16 row-major
    _Float16* __restrict__ ET)        // [B][H][N] fp16 transposed
{
    constexpr int XP = 164;                     // x pitch (halves)
    __shared__ __align__(16) _Float16 xs[32 * XP];   // 10.5 KB; aliased w/ es
    __shared__ __align__(16) float hbF[2][32 * 64];  // 16 KB f32 h exchange
    __shared__ float ap[2][32];                 // attn partials per wave
    float* es = (float*)xs;                     // [32][65] epilogue bounce

    const int tid  = threadIdx.x;
    const int w    = tid >> 6;                  // wave id (0,1)
    const int lane = tid & 63;
    const int m    = lane & 31;                 // seq column
    const int hi   = lane >> 5;

    // ---- stage x (fp32 -> fp16 LDS) ----
    const float* xg = x + (size_t)blockIdx.x * 32 * Tc * Fc;
    for (int i = tid; i < 32 * 160; i += 128) {
        int mm = i / 160, o = i - mm * 160;
        xs[mm * XP + o] = (_Float16)xg[i];
    }

    // per-gate exp2 folding scales (gate order i,f,g,o)
    constexpr float L2E = 1.4426950408889634f;
    const float gsc[4] = {-L2E, -L2E, 2.f * L2E, -L2E};

    // ---- preload A fragments: af[g][kt], jt = 2g+w, row j = 32*jt + m ----
    f16x8 af[4][5];
    #pragma unroll
    for (int g = 0; g < 4; ++g) {
        const int j = 32 * (2 * g + w) + m;     // = 64g + 32w + m
        const float sc = gsc[g];
        #pragma unroll
        for (int kt = 0; kt < 4; ++kt) {
            const float* wp = Whh + j * 64 + kt * 16 + 8 * hi;
            float4 u0 = *(const float4*)wp;
            float4 u1 = *(const float4*)(wp + 4);
            af[g][kt] = f16x8{(_Float16)(sc * u0.x), (_Float16)(sc * u0.y),
                              (_Float16)(sc * u0.z), (_Float16)(sc * u0.w),
                              (_Float16)(sc * u1.x), (_Float16)(sc * u1.y),
                              (_Float16)(sc * u1.z), (_Float16)(sc * u1.w)};
        }
        float v[8];
        #pragma unroll
        for (int e = 0; e < 5; ++e) v[e] = sc * Wih[j * Fc + e];
        v[5] = sc * (bih[j] + bhh[j]); v[6] = 0.f; v[7] = 0.f;
        #pragma unroll
        for (int e = 0; e < 8; ++e) {
            float z = hi ? 0.f : v[e];
            af[g][4][e] = (_Float16)z;
        }
    }

    // attention weights for owned units u = 32w + 8a2 + 4hi + p
    float aw_own[16];
    #pragma unroll
    for (int a2 = 0; a2 < 4; ++a2)
        #pragma unroll
        for (int p = 0; p < 4; ++p)
            aw_own[a2 * 4 + p] = attn_w[32 * w + 8 * a2 + 4 * hi + p];
    const float ab = attn_b[0];

    float hcur[16], cst[16], oacc[16];
    #pragma unroll
    for (int i = 0; i < 16; ++i) { hcur[i] = 0.f; cst[i] = 0.f; oacc[i] = 0.f; }
    float lsum = 0.f;

    f32x16 zero16 = {0,0,0,0,0,0,0,0,0,0,0,0,0,0,0,0};
    const int xrow = m * XP;
    const int swz  = m & 15;                    // 16B-chunk XOR swizzle
    __syncthreads();

    // ---- initial B fragments: h(0)=0 directly, x(0) row ----
    f16x8 bf[5];
    #pragma unroll
    for (int kt = 0; kt < 5; ++kt)
        #pragma unroll
        for (int e = 0; e < 8; ++e) bf[kt][e] = (_Float16)0.f;
    if (!hi) {
        #pragma unroll
        for (int e = 0; e < 5; ++e) bf[4][e] = xs[xrow + e];
        bf[4][5] = (_Float16)1.f;
    }

    #pragma unroll 1
    for (int t = 0; t < Tc; ++t) {
        // ---- per-gate MFMA chain -> immediate exp2 into plain VGPRs ----
        float eg0[16], eg1[16], eg2[16], eg3[16];
        #pragma unroll
        for (int g = 0; g < 4; ++g) {
            f32x16 acc = __builtin_amdgcn_mfma_f32_32x32x16_f16(af[g][0], bf[0], zero16, 0, 0, 0);
            #pragma unroll
            for (int kt = 1; kt < 5; ++kt)
                acc = __builtin_amdgcn_mfma_f32_32x32x16_f16(af[g][kt], bf[kt], acc, 0, 0, 0);
            float* dst = (g == 0) ? eg0 : (g == 1) ? eg1 : (g == 2) ? eg2 : eg3;
            #pragma unroll
            for (int r = 0; r < 16; ++r) dst[r] = exp2_fast(acc[r]);
        }
        // ---- combine: ei=eg0, ef=eg1, Eg=eg2, eo=eg3 ----
        float attnp = 0.f;
        #pragma unroll
        for (int r = 0; r < 16; ++r) {
            float u  = 1.f + eg0[r];
            float v  = 1.f + eg1[r];
            float wq = eg2[r] + 1.f;
            float z  = eg2[r] - 1.f;
            float t1 = u * wq;
            float num = fmaf(cst[r], t1, z * v);
            float cn = num * fast_rcp(t1 * v);
            cst[r] = cn;
            float E2 = exp2_fast(2.f * L2E * cn);   // e^{2c}
            float hv = (E2 - 1.f) * fast_rcp((E2 + 1.f) * (1.f + eg3[r]));
            hcur[r] = hv;
            attnp = fmaf(hv, aw_own[r], attnp);
        }
        // ---- publish h as raw f32 (zero cvt) + attention partial ----
        float* hw = &hbF[(t + 1) & 1][0];
        #pragma unroll
        for (int a2 = 0; a2 < 4; ++a2)
            *(float4*)&hw[m * 64 + (((8 * w + 2 * a2 + hi) ^ swz) * 4)] =
                float4{hcur[4 * a2 + 0], hcur[4 * a2 + 1],
                       hcur[4 * a2 + 2], hcur[4 * a2 + 3]};
        attnp += __shfl_xor(attnp, 32);
        if (!hi) ap[w][m] = attnp;
        __syncthreads();
        // ---- score + online accumulation (both waves identical) ----
        float sc = tanh_fast(ap[0][m] + ap[1][m] + ab);
        float ew = __expf(sc);
        lsum += ew;
        #pragma unroll
        for (int i = 0; i < 16; ++i) oacc[i] = fmaf(ew, hcur[i], oacc[i]);
        // ---- build next B fragments (f32 reads, cvt once) ----
        if (t != Tc - 1) {
            const float* hr = &hbF[(t + 1) & 1][0];
            #pragma unroll
            for (int kt = 0; kt < 4; ++kt) {
                float4 lo = *(const float4*)&hr[m * 64 + (((4 * kt + 2 * hi)     ^ swz) * 4)];
                float4 hh = *(const float4*)&hr[m * 64 + (((4 * kt + 2 * hi + 1) ^ swz) * 4)];
                bf[kt] = f16x8{(_Float16)lo.x, (_Float16)lo.y, (_Float16)lo.z, (_Float16)lo.w,
                               (_Float16)hh.x, (_Float16)hh.y, (_Float16)hh.z, (_Float16)hh.w};
            }
            if (!hi) {
                #pragma unroll
                for (int e = 0; e < 5; ++e) bf[4][e] = xs[xrow + (t + 1) * Fc + e];
                bf[4][5] = (_Float16)1.f;
            }
        }
    }

    // ---- epilogue: es[m][u] = oacc/lsum, then E16 + ET ----
    __syncthreads();                    // xs reads done before aliasing
    const float li = fast_rcp(lsum);
    #pragma unroll
    for (int r = 0; r < 16; ++r) {
        int u = 32 * w + 8 * (r >> 2) + 4 * hi + (r & 3);
        es[m * 65 + u] = oacc[r] * li;
    }
    __syncthreads();

    uint* E16u = (uint*)E16 + (size_t)blockIdx.x * 32 * 32;
    for (int idx = tid; idx < 32 * 32; idx += 128) {
        int mm = idx >> 5, hp = idx & 31;
        union { _Float16 h2[2]; uint u; } cv;
        cv.h2[0] = (_Float16)es[mm * 65 + 2 * hp];
        cv.h2[1] = (_Float16)es[mm * 65 + 2 * hp + 1];
        E16u[idx] = cv.u;
    }
    const int bb_ = blockIdx.x >> 5, n0d = (blockIdx.x & 31) * 16;
    uint* ETu = (uint*)ET;
    for (int idx = tid; idx < 64 * 16; idx += 128) {
        int h = idx >> 4, c = idx & 15;
        union { _Float16 h2[2]; uint u; } cv;
        cv.h2[0] = (_Float16)es[(2 * c) * 65 + h];
        cv.h2[1] = (_Float16)es[(2 * c + 1) * 65 + h];
        ETu[((size_t)bb_ * 64 + h) * 512 + n0d + c] = cv.u;
    }
}

// ---------------- Kernel 2: edge coefficients, LDS-bounce version -----------
__global__ __launch_bounds__(256, 4) void coefq_kernel(
    const float* __restrict__ A,     // [N, N, R]
    const float* __restrict__ gnn_w, // [R]
    const float* __restrict__ gnn_b, // [1]
    float* __restrict__ coefQ,       // [N/4][N][4]
    float* __restrict__ degP)        // [32][N] partial counts
{
    constexpr int CP = 162;                 // float pitch
    __shared__ float as[32 * CP];           // 20.7 KB
    __shared__ float dcnt[4][32];
    const int t  = threadIdx.x;
    const int it = blockIdx.x >> 5, jt = blockIdx.x & 31;

    float gw[5];
    #pragma unroll
    for (int f = 0; f < 5; ++f) gw[f] = gnn_w[f];
    const float gb = gnn_b[0];

    // ---- stage 32 rows x 160 floats (coalesced float2) ----
    const float* src = A + ((size_t)it * 32 * 1024 + jt * 32) * 5;
    #pragma unroll
    for (int k = 0; k < 10; ++k) {
        int idx = t + k * 256;              // 0..2559
        int row = idx / 80, c2 = idx - row * 80;
        *(float2*)&as[row * CP + c2 * 2] = *(const float2*)(src + (size_t)row * 5120 + c2 * 2);
    }
    __syncthreads();

    // ---- compute: thread (g = t>>5, i = t&31) handles j-quad g ----
    const int g = t >> 5, i_loc = t & 31;
    float cf[4]; float cnt = 0.f;
    #pragma unroll
    for (int q = 0; q < 4; ++q) {
        const float* ap = &as[i_loc * CP + (g * 4 + q) * 5];
        float s = 0.f, d = gb;
        #pragma unroll
        for (int f = 0; f < 5; ++f) { float vv = ap[f]; s += vv; d = fmaf(vv, gw[f], d); }
        cf[q] = (s > 0.f) ? (d >= 0.f ? d : 0.2f * d) : 0.f;
        cnt += (s > 0.f) ? 1.f : 0.f;
    }
    ((float4*)coefQ)[(size_t)(jt * 8 + g) * 1024 + it * 32 + i_loc] =
        float4{cf[0], cf[1], cf[2], cf[3]};

    // ---- degree partial: sum over the 8 g-groups for each i ----
    cnt += __shfl_xor(cnt, 32);             // combine g pairs within wave
    if ((t & 32) == 0) dcnt[t >> 6][i_loc] = cnt;
    __syncthreads();
    if (t < 32)
        degP[jt * 1024 + it * 32 + t] = dcnt[0][t] + dcnt[1][t] + dcnt[2][t] + dcnt[3][t];
}

// ---------------- Kernel 3: MFMA GNN message pass + prediction head ---------
__global__ __launch_bounds__(256, 2) void gnn_pred_kernel(
    const _Float16* __restrict__ E16,  // [B*N, H]
    const _Float16* __restrict__ ET,   // [B][H][N]
    const float* __restrict__ coefQ,   // [N/4][N][4]
    const float* __restrict__ degP,    // [32][N]
    const float* __restrict__ pred_w,  // [2H]
    const float* __restrict__ pred_b,  // [1]
    float* __restrict__ preds)         // [B*N]
{
    __shared__ __align__(16) _Float16 tiles[2][4][64 * 64];  // 64 KB exactly
    const int tid  = threadIdx.x;
    const int w    = tid >> 6;
    const int lane = tid & 63;
    const int l31  = lane & 31;
    const int hi   = lane >> 5;
    const int it   = blockIdx.x >> 5;           // it-major (XCD locality)
    const int b    = blockIdx.x & 31;

    _Float16* EA = &tiles[0][w][0];
    _Float16* EB = &tiles[1][w][0];
    const float4* coefQ4 = (const float4*)coefQ;

    f16x8 eb[2][4];
    #pragma unroll
    for (int ni = 0; ni < 2; ++ni)
        #pragma unroll
        for (int kt = 0; kt < 4; ++kt)
            eb[ni][kt] = *(const f16x8*)(E16 +
                ((size_t)(b * 1024 + it * 64 + ni * 32 + l31) * 64 + 16 * kt + 8 * hi));

    f32x16 zero16 = {0,0,0,0,0,0,0,0,0,0,0,0,0,0,0,0};
    f32x16 oacc[2][2];
    #pragma unroll
    for (int mi = 0; mi < 2; ++mi)
        #pragma unroll
        for (int nh = 0; nh < 2; ++nh) oacc[mi][nh] = zero16;

    #pragma unroll 1
    for (int s = 0; s < 4; ++s) {
        const int jt = w * 4 + s;
        const _Float16* srcA = E16 + (size_t)(b * 1024 + jt * 64) * 64;
        const _Float16* srcB = ET + (size_t)b * 64 * 1024 + jt * 64;
        #pragma unroll
        for (int q = 0; q < 8; ++q) {
            int f = q * 64 + lane, r = f >> 3, c = f & 7;
            uint4 va = *(const uint4*)(srcA + r * 64 + c * 8);
            *(uint4*)(EA + r * 64 + ((c ^ (r & 7)) * 8)) = va;
            uint4 vb = *(const uint4*)(srcB + r * 1024 + c * 8);
            *(uint4*)(EB + r * 64 + ((c ^ (r & 7)) * 8)) = vb;
        }
        #pragma unroll 1
        for (int mj = 0; mj < 2; ++mj) {
            f16x8 af[4];
            #pragma unroll
            for (int kt = 0; kt < 4; ++kt)
                af[kt] = *(const f16x8*)(EA + (mj * 32 + l31) * 64 +
                                         (((2 * kt + hi) ^ (l31 & 7)) * 8));
            #pragma unroll
            for (int mi = 0; mi < 2; ++mi) {
                // S' = Ej . Ei^T  (16 regs live)
                f32x16 a = __builtin_amdgcn_mfma_f32_32x32x16_f16(af[0], eb[mi][0], zero16, 0, 0, 0);
                #pragma unroll
                for (int kt = 1; kt < 4; ++kt)
                    a = __builtin_amdgcn_mfma_f32_32x32x16_f16(af[kt], eb[mi][kt], a, 0, 0, 0);
                // P = S' * coef
                #pragma unroll
                for (int rg = 0; rg < 4; ++rg) {
                    int j0 = jt * 64 + mj * 32 + 8 * rg + 4 * hi;
                    float4 cf = coefQ4[(size_t)(j0 >> 2) * 1024 + it * 64 + mi * 32 + l31];
                    a[4 * rg + 0] *= cf.x; a[4 * rg + 1] *= cf.y;
                    a[4 * rg + 2] *= cf.z; a[4 * rg + 3] *= cf.w;
                }
                // pack C-layout -> fp16 A-frags via lane^32 swap
                f16x8 pa[2];
                #pragma unroll
                for (int kk = 0; kk < 2; ++kk) {
                    const int rg = 2 * kk;
                    #pragma unroll
                    for (int c4 = 0; c4 < 4; ++c4) {
                        float own_lo = a[rg * 4 + c4];
                        float own_hi = a[(rg + 1) * 4 + c4];
                        float send = hi ? own_lo : own_hi;
                        float recv = __shfl_xor(send, 32);
                        float lo = hi ? recv : own_lo;
                        float hv = hi ? own_hi : recv;
                        pa[kk][c4]     = (_Float16)lo;
                        pa[kk][4 + c4] = (_Float16)hv;
                    }
                }
                // O += P . Ej
                #pragma unroll
                for (int nh = 0; nh < 2; ++nh)
                    #pragma unroll
                    for (int kk = 0; kk < 2; ++kk) {
                        const int ktj = 2 * mj + kk;
                        f16x8 bb = *(const f16x8*)(EB + (nh * 32 + l31) * 64 +
                                                   (((2 * ktj + hi) ^ (l31 & 7)) * 8));
                        oacc[mi][nh] = __builtin_amdgcn_mfma_f32_32x32x16_f16(
                            pa[kk], bb, oacc[mi][nh], 0, 0, 0);
                    }
            }
        }
    }

    // ---- epilogue: per-wave O.pwh partials -> LDS (aliases dead EA tile) ---
    float* pacc = (float*)&tiles[0][w][0];      // 64 floats, wave-private
    const float pwh0 = pred_w[64 + l31];
    const float pwh1 = pred_w[96 + l31];
    #pragma unroll
    for (int mi = 0; mi < 2; ++mi)
        #pragma unroll
        for (int r = 0; r < 16; ++r) {
            float v = oacc[mi][0][r] * pwh0 + oacc[mi][1][r] * pwh1;
            v += __shfl_xor(v, 1);  v += __shfl_xor(v, 2);  v += __shfl_xor(v, 4);
            v += __shfl_xor(v, 8);  v += __shfl_xor(v, 16);
            int i_loc = mi * 32 + 8 * (r >> 2) + (r & 3) + 4 * hi;
            if (l31 == 0) pacc[i_loc] = v;
        }
    __syncthreads();
    if (w == 0) {
        const float pb0 = pred_b[0];
        #pragma unroll
        for (int ni = 0; ni < 2; ++ni) {
            float dot = 0.f;
            #pragma unroll
            for (int kt = 0; kt < 4; ++kt)
                #pragma unroll
                for (int e = 0; e < 8; ++e)
                    dot = fmaf((float)eb[ni][kt][e], pred_w[16 * kt + 8 * hi + e], dot);
            dot += __shfl_xor(dot, 32);
            if (hi == 0) {
                int i_loc = ni * 32 + l31;
                int gi = it * 64 + i_loc;
                float osum = ((float*)&tiles[0][0][0])[i_loc] +
                             ((float*)&tiles[0][1][0])[i_loc] +
                             ((float*)&tiles[0][2][0])[i_loc] +
                             ((float*)&tiles[0][3][0])[i_loc];
                float dsum = 0.f;
                #pragma unroll
                for (int jj = 0; jj < 32; ++jj) dsum += degP[jj * 1024 + gi];
                preds[b * 1024 + gi] = dot + osum * fast_rcp(dsum) + pb0;
            }
        }
    }
}

extern "C" void kernel_launch(void* const* d_in, const int* in_sizes, int n_in,
                              void* d_out, int out_size, void* d_ws, size_t ws_size,
                              hipStream_t stream) {
    const float* x      = (const float*)d_in[0];
    const float* A      = (const float*)d_in[1];
    const float* Wih    = (const float*)d_in[2];
    const float* Whh    = (const float*)d_in[3];
    const float* bih    = (const float*)d_in[4];
    const float* bhh    = (const float*)d_in[5];
    const float* attn_w = (const float*)d_in[6];
    const float* attn_b = (const float*)d_in[7];
    const float* gnn_w  = (const float*)d_in[8];
    const float* gnn_b  = (const float*)d_in[9];
    const float* pred_w = (const float*)d_in[10];
    const float* pred_b = (const float*)d_in[11];
    float* preds = (float*)d_out;

    // ws: E16 (4MB) | ET (4MB) | coefQ (4MB) | degP (128KB)
    _Float16* E16 = (_Float16*)d_ws;
    _Float16* ET  = E16 + (size_t)BNc * Hc;
    float* coefQ  = (float*)(ET + (size_t)BNc * Hc);
    float* degP   = coefQ + (size_t)Nc * Nc;

    lstm_attn_kernel<<<BNc / 32, 128, 0, stream>>>(x, Wih, Whh, bih, bhh,
                                                   attn_w, attn_b, E16, ET);
    coefq_kernel<<<1024, 256, 0, stream>>>(A, gnn_w, gnn_b, coefQ, degP);
    gnn_pred_kernel<<<Bc * (Nc / 64), 256, 0, stream>>>(E16, ET, coefQ, degP,
                                                        pred_w, pred_b, preds);
}

// Round 11
// 217.900 us; speedup vs baseline: 1.1626x; 1.0029x over previous
//
#include <hip/hip_runtime.h>

// Problem constants (B,N,T,F,H,R) = (32,1024,32,5,64,5)
constexpr int Bc = 32, Nc = 1024, Tc = 32, Fc = 5, Hc = 64;
constexpr int BNc = Bc * Nc;   // 32768 sequences

#define DEVFN __device__ __forceinline__

typedef _Float16 f16x8 __attribute__((ext_vector_type(8)));
typedef _Float16 f16x4 __attribute__((ext_vector_type(4)));
typedef float    f32x16 __attribute__((ext_vector_type(16)));

DEVFN float fast_rcp(float x) { return __builtin_amdgcn_rcpf(x); }
DEVFN float tanh_fast(float x) { return 1.f - 2.f * fast_rcp(__expf(2.f * x) + 1.f); }

#if __has_builtin(__builtin_amdgcn_exp2f)
DEVFN float exp2_fast(float x) { return __builtin_amdgcn_exp2f(x); }
#else
DEVFN float exp2_fast(float x) { return exp2f(x); }
#endif

// ---------------- Kernel 1: fused LSTM + temporal attention (MFMA) ----------
// R9 version exactly (best measured: 112.9 µs): 2 waves x 32 seqs, wave owns
// 32 units, exp2-folded weights (gate rows pre-scaled by {-log2e,-log2e,
// +2log2e,-log2e}), fused-denominator cell algebra (5 exp2 + 2 rcp per unit),
// pitch-64 swizzled fp16 h-exchange.
__global__ __launch_bounds__(128, 2) void lstm_attn_kernel(
    const float* __restrict__ x,      // [BN, T, F]
    const float* __restrict__ Wih,    // [4H, F]
    const float* __restrict__ Whh,    // [4H, H]
    const float* __restrict__ bih,    // [4H]
    const float* __restrict__ bhh,    // [4H]
    const float* __restrict__ attn_w, // [H]
    const float* __restrict__ attn_b, // [1]
    _Float16* __restrict__ E16,       // [B*N, H] fp16 row-major
    _Float16* __restrict__ ET)        // [B][H][N] fp16 transposed
{
    constexpr int XP = 164;                     // x pitch (halves)
    __shared__ __align__(16) _Float16 xs[32 * XP];   // 10.5 KB; aliased w/ es
    __shared__ __align__(16) _Float16 hb[2][32 * 64];// 8 KB h exchange
    __shared__ float ap[2][32];                 // attn partials per wave
    float* es = (float*)xs;                     // [32][65] epilogue bounce

    const int tid  = threadIdx.x;
    const int w    = tid >> 6;                  // wave id (0,1)
    const int lane = tid & 63;
    const int m    = lane & 31;                 // seq column
    const int hi   = lane >> 5;

    // ---- stage x (fp32 -> fp16 LDS) ----
    const float* xg = x + (size_t)blockIdx.x * 32 * Tc * Fc;
    for (int i = tid; i < 32 * 160; i += 128) {
        int mm = i / 160, o = i - mm * 160;
        xs[mm * XP + o] = (_Float16)xg[i];
    }
    // zero h buffer 0
    for (int i = tid; i < 1024; i += 128) ((uint*)&hb[0][0])[i] = 0u;

    // per-gate exp2 folding scales (gate order i,f,g,o)
    constexpr float L2E = 1.4426950408889634f;
    const float gsc[4] = {-L2E, -L2E, 2.f * L2E, -L2E};

    // ---- preload A fragments: af[g][kt], jt = 2g+w, row j = 32*jt + m ----
    f16x8 af[4][5];
    #pragma unroll
    for (int g = 0; g < 4; ++g) {
        const int j = 32 * (2 * g + w) + m;     // = 64g + 32w + m
        const float sc = gsc[g];
        #pragma unroll
        for (int kt = 0; kt < 4; ++kt) {
            const float* wp = Whh + j * 64 + kt * 16 + 8 * hi;
            float4 u0 = *(const float4*)wp;
            float4 u1 = *(const float4*)(wp + 4);
            af[g][kt] = f16x8{(_Float16)(sc * u0.x), (_Float16)(sc * u0.y),
                              (_Float16)(sc * u0.z), (_Float16)(sc * u0.w),
                              (_Float16)(sc * u1.x), (_Float16)(sc * u1.y),
                              (_Float16)(sc * u1.z), (_Float16)(sc * u1.w)};
        }
        float v[8];
        #pragma unroll
        for (int e = 0; e < 5; ++e) v[e] = sc * Wih[j * Fc + e];
        v[5] = sc * (bih[j] + bhh[j]); v[6] = 0.f; v[7] = 0.f;
        #pragma unroll
        for (int e = 0; e < 8; ++e) {
            float z = hi ? 0.f : v[e];
            af[g][4][e] = (_Float16)z;
        }
    }

    // attention weights for owned units u = 32w + 8a2 + 4hi + p
    float aw_own[16];
    #pragma unroll
    for (int a2 = 0; a2 < 4; ++a2)
        #pragma unroll
        for (int p = 0; p < 4; ++p)
            aw_own[a2 * 4 + p] = attn_w[32 * w + 8 * a2 + 4 * hi + p];
    const float ab = attn_b[0];

    float hcur[16], cst[16], oacc[16];
    #pragma unroll
    for (int i = 0; i < 16; ++i) { hcur[i] = 0.f; cst[i] = 0.f; oacc[i] = 0.f; }
    float lsum = 0.f;

    f32x16 zero16 = {0,0,0,0,0,0,0,0,0,0,0,0,0,0,0,0};
    const int xrow = m * XP;
    const int swz  = m & 15;                    // chunk XOR swizzle
    __syncthreads();

    // ---- initial B fragments from hb[0] (zeros) + x(0) ----
    f16x8 bf[5];
    #pragma unroll
    for (int kt = 0; kt < 4; ++kt) {
        f16x4 lo = *(const f16x4*)&hb[0][m * 64 + ((4 * kt + 2 * hi)     ^ swz) * 4];
        f16x4 hh = *(const f16x4*)&hb[0][m * 64 + ((4 * kt + 2 * hi + 1) ^ swz) * 4];
        bf[kt] = f16x8{lo[0], lo[1], lo[2], lo[3], hh[0], hh[1], hh[2], hh[3]};
    }
    {
        #pragma unroll
        for (int e = 0; e < 8; ++e) bf[4][e] = (_Float16)0.f;
        if (!hi) {
            #pragma unroll
            for (int e = 0; e < 5; ++e) bf[4][e] = xs[xrow + e];
            bf[4][5] = (_Float16)1.f;
        }
    }

    #pragma unroll 1
    for (int t = 0; t < Tc; ++t) {
        // ---- gates: 4 gate tiles x 5 k-tiles ----
        f32x16 acc[4];
        #pragma unroll
        for (int g = 0; g < 4; ++g) {
            acc[g] = __builtin_amdgcn_mfma_f32_32x32x16_f16(af[g][0], bf[0], zero16, 0, 0, 0);
            #pragma unroll
            for (int kt = 1; kt < 5; ++kt)
                acc[g] = __builtin_amdgcn_mfma_f32_32x32x16_f16(af[g][kt], bf[kt], acc[g], 0, 0, 0);
        }
        // ---- cell update: 5 exp2 + 2 rcp per unit (weights pre-scaled) ----
        float attnp = 0.f;
        #pragma unroll
        for (int r = 0; r < 16; ++r) {
            float ei = exp2_fast(acc[0][r]);        // e^{-i}
            float ef = exp2_fast(acc[1][r]);        // e^{-f}
            float Eg = exp2_fast(acc[2][r]);        // e^{2g}
            float eo = exp2_fast(acc[3][r]);        // e^{-o}
            float u  = 1.f + ei;
            float v  = 1.f + ef;
            float wq = Eg + 1.f;
            float z  = Eg - 1.f;
            float t1 = u * wq;
            float num = fmaf(cst[r], t1, z * v);
            float cn = num * fast_rcp(t1 * v);
            cst[r] = cn;
            float E2 = exp2_fast(2.f * L2E * cn);   // e^{2c}
            float hv = (E2 - 1.f) * fast_rcp((E2 + 1.f) * (1.f + eo));
            hcur[r] = hv;
            attnp = fmaf(hv, aw_own[r], attnp);
        }
        // ---- publish h (fp16, swizzled chunks) + attention partial ----
        _Float16* hw = &hb[(t + 1) & 1][0];
        #pragma unroll
        for (int a2 = 0; a2 < 4; ++a2) {
            f16x4 pk = {(_Float16)hcur[4 * a2 + 0], (_Float16)hcur[4 * a2 + 1],
                        (_Float16)hcur[4 * a2 + 2], (_Float16)hcur[4 * a2 + 3]};
            *(f16x4*)&hw[m * 64 + ((8 * w + 2 * a2 + hi) ^ swz) * 4] = pk;
        }
        attnp += __shfl_xor(attnp, 32);
        if (!hi) ap[w][m] = attnp;
        __syncthreads();
        // ---- score + online accumulation (both waves identical) ----
        float sc = tanh_fast(ap[0][m] + ap[1][m] + ab);
        float ew = __expf(sc);
        lsum += ew;
        #pragma unroll
        for (int i = 0; i < 16; ++i) oacc[i] = fmaf(ew, hcur[i], oacc[i]);
        // ---- build next B fragments ----
        if (t != Tc - 1) {
            const _Float16* hr = &hb[(t + 1) & 1][0];
            #pragma unroll
            for (int kt = 0; kt < 4; ++kt) {
                f16x4 lo = *(const f16x4*)&hr[m * 64 + ((4 * kt + 2 * hi)     ^ swz) * 4];
                f16x4 hh = *(const f16x4*)&hr[m * 64 + ((4 * kt + 2 * hi + 1) ^ swz) * 4];
                bf[kt] = f16x8{lo[0], lo[1], lo[2], lo[3], hh[0], hh[1], hh[2], hh[3]};
            }
            if (!hi) {
                #pragma unroll
                for (int e = 0; e < 5; ++e) bf[4][e] = xs[xrow + (t + 1) * Fc + e];
                bf[4][5] = (_Float16)1.f;
            }
        }
    }

    // ---- epilogue: es[m][u] = oacc/lsum, then E16 + ET ----
    __syncthreads();                    // xs reads done before aliasing
    const float li = fast_rcp(lsum);
    #pragma unroll
    for (int r = 0; r < 16; ++r) {
        int u = 32 * w + 8 * (r >> 2) + 4 * hi + (r & 3);
        es[m * 65 + u] = oacc[r] * li;
    }
    __syncthreads();

    uint* E16u = (uint*)E16 + (size_t)blockIdx.x * 32 * 32;
    for (int idx = tid; idx < 32 * 32; idx += 128) {
        int mm = idx >> 5, hp = idx & 31;
        union { _Float16 h2[2]; uint u; } cv;
        cv.h2[0] = (_Float16)es[mm * 65 + 2 * hp];
        cv.h2[1] = (_Float16)es[mm * 65 + 2 * hp + 1];
        E16u[idx] = cv.u;
    }
    const int bb_ = blockIdx.x >> 5, n0d = (blockIdx.x & 31) * 16;
    uint* ETu = (uint*)ET;
    for (int idx = tid; idx < 64 * 16; idx += 128) {
        int h = idx >> 4, c = idx & 15;
        union { _Float16 h2[2]; uint u; } cv;
        cv.h2[0] = (_Float16)es[(2 * c) * 65 + h];
        cv.h2[1] = (_Float16)es[(2 * c + 1) * 65 + h];
        ETu[((size_t)bb_ * 64 + h) * 512 + n0d + c] = cv.u;
    }
}

// ---------------- Kernel 2: edge coefficients (fp16 packed) + degree --------
// Same structure as R8-R10; coefQ now stored fp16 (halves write + gnn read
// streams; coef rel-err 2^-11 contributes ~1e-5 absolute to preds).
__global__ __launch_bounds__(256, 4) void coefq_kernel(
    const float* __restrict__ A,     // [N, N, R]
    const float* __restrict__ gnn_w, // [R]
    const float* __restrict__ gnn_b, // [1]
    _Float16* __restrict__ coefQH,   // [N/4][N][4] fp16
    float* __restrict__ degP)        // [32][N] partial counts
{
    constexpr int CP = 162;                 // float pitch
    __shared__ float as[32 * CP];           // 20.7 KB
    __shared__ float dcnt[4][32];
    const int t  = threadIdx.x;
    const int it = blockIdx.x >> 5, jt = blockIdx.x & 31;

    float gw[5];
    #pragma unroll
    for (int f = 0; f < 5; ++f) gw[f] = gnn_w[f];
    const float gb = gnn_b[0];

    // ---- stage 32 rows x 160 floats (coalesced float2) ----
    const float* src = A + ((size_t)it * 32 * 1024 + jt * 32) * 5;
    #pragma unroll
    for (int k = 0; k < 10; ++k) {
        int idx = t + k * 256;              // 0..2559
        int row = idx / 80, c2 = idx - row * 80;
        *(float2*)&as[row * CP + c2 * 2] = *(const float2*)(src + (size_t)row * 5120 + c2 * 2);
    }
    __syncthreads();

    // ---- compute: thread (g = t>>5, i = t&31) handles j-quad g ----
    const int g = t >> 5, i_loc = t & 31;
    float cf[4]; float cnt = 0.f;
    #pragma unroll
    for (int q = 0; q < 4; ++q) {
        const float* ap = &as[i_loc * CP + (g * 4 + q) * 5];
        float s = 0.f, d = gb;
        #pragma unroll
        for (int f = 0; f < 5; ++f) { float vv = ap[f]; s += vv; d = fmaf(vv, gw[f], d); }
        cf[q] = (s > 0.f) ? (d >= 0.f ? d : 0.2f * d) : 0.f;
        cnt += (s > 0.f) ? 1.f : 0.f;
    }
    ((f16x4*)coefQH)[(size_t)(jt * 8 + g) * 1024 + it * 32 + i_loc] =
        f16x4{(_Float16)cf[0], (_Float16)cf[1], (_Float16)cf[2], (_Float16)cf[3]};

    // ---- degree partial: sum over the 8 g-groups for each i ----
    cnt += __shfl_xor(cnt, 32);             // combine g pairs within wave
    if ((t & 32) == 0) dcnt[t >> 6][i_loc] = cnt;
    __syncthreads();
    if (t < 32)
        degP[jt * 1024 + it * 32 + t] = dcnt[0][t] + dcnt[1][t] + dcnt[2][t] + dcnt[3][t];
}

// ---------------- Kernel 3: MFMA GNN message pass + prediction head ---------
__global__ __launch_bounds__(256, 2) void gnn_pred_kernel(
    const _Float16* __restrict__ E16,  // [B*N, H]
    const _Float16* __restrict__ ET,   // [B][H][N]
    const _Float16* __restrict__ coefQH,// [N/4][N][4] fp16
    const float* __restrict__ degP,    // [32][N]
    const float* __restrict__ pred_w,  // [2H]
    const float* __restrict__ pred_b,  // [1]
    float* __restrict__ preds)         // [B*N]
{
    __shared__ __align__(16) _Float16 tiles[2][4][64 * 64];  // 64 KB exactly
    const int tid  = threadIdx.x;
    const int w    = tid >> 6;
    const int lane = tid & 63;
    const int l31  = lane & 31;
    const int hi   = lane >> 5;
    const int it   = blockIdx.x >> 5;           // it-major (XCD locality)
    const int b    = blockIdx.x & 31;

    _Float16* EA = &tiles[0][w][0];
    _Float16* EB = &tiles[1][w][0];
    const f16x4* cq = (const f16x4*)coefQH;

    f16x8 eb[2][4];
    #pragma unroll
    for (int ni = 0; ni < 2; ++ni)
        #pragma unroll
        for (int kt = 0; kt < 4; ++kt)
            eb[ni][kt] = *(const f16x8*)(E16 +
                ((size_t)(b * 1024 + it * 64 + ni * 32 + l31) * 64 + 16 * kt + 8 * hi));

    f32x16 zero16 = {0,0,0,0,0,0,0,0,0,0,0,0,0,0,0,0};
    f32x16 oacc[2][2];
    #pragma unroll
    for (int mi = 0; mi < 2; ++mi)
        #pragma unroll
        for (int nh = 0; nh < 2; ++nh) oacc[mi][nh] = zero16;

    #pragma unroll 1
    for (int s = 0; s < 4; ++s) {
        const int jt = w * 4 + s;
        const _Float16* srcA = E16 + (size_t)(b * 1024 + jt * 64) * 64;
        const _Float16* srcB = ET + (size_t)b * 64 * 1024 + jt * 64;
        #pragma unroll
        for (int q = 0; q < 8; ++q) {
            int f = q * 64 + lane, r = f >> 3, c = f & 7;
            uint4 va = *(const uint4*)(srcA + r * 64 + c * 8);
            *(uint4*)(EA + r * 64 + ((c ^ (r & 7)) * 8)) = va;
            uint4 vb = *(const uint4*)(srcB + r * 1024 + c * 8);
            *(uint4*)(EB + r * 64 + ((c ^ (r & 7)) * 8)) = vb;
        }
        #pragma unroll 1
        for (int mj = 0; mj < 2; ++mj) {
            f16x8 af[4];
            #pragma unroll
            for (int kt = 0; kt < 4; ++kt)
                af[kt] = *(const f16x8*)(EA + (mj * 32 + l31) * 64 +
                                         (((2 * kt + hi) ^ (l31 & 7)) * 8));
            #pragma unroll
            for (int mi = 0; mi < 2; ++mi) {
                // S' = Ej . Ei^T  (16 regs live)
                f32x16 a = __builtin_amdgcn_mfma_f32_32x32x16_f16(af[0], eb[mi][0], zero16, 0, 0, 0);
                #pragma unroll
                for (int kt = 1; kt < 4; ++kt)
                    a = __builtin_amdgcn_mfma_f32_32x32x16_f16(af[kt], eb[mi][kt], a, 0, 0, 0);
                // P = S' * coef (fp16 coef, 8B per lane)
                #pragma unroll
                for (int rg = 0; rg < 4; ++rg) {
                    int j0 = jt * 64 + mj * 32 + 8 * rg + 4 * hi;
                    f16x4 cfh = cq[(size_t)(j0 >> 2) * 1024 + it * 64 + mi * 32 + l31];
                    a[4 * rg + 0] *= (float)cfh[0]; a[4 * rg + 1] *= (float)cfh[1];
                    a[4 * rg + 2] *= (float)cfh[2]; a[4 * rg + 3] *= (float)cfh[3];
                }
                // pack C-layout -> fp16 A-frags via lane^32 swap
                f16x8 pa[2];
                #pragma unroll
                for (int kk = 0; kk < 2; ++kk) {
                    const int rg = 2 * kk;
                    #pragma unroll
                    for (int c4 = 0; c4 < 4; ++c4) {
                        float own_lo = a[rg * 4 + c4];
                        float own_hi = a[(rg + 1) * 4 + c4];
                        float send = hi ? own_lo : own_hi;
                        float recv = __shfl_xor(send, 32);
                        float lo = hi ? recv : own_lo;
                        float hv = hi ? own_hi : recv;
                        pa[kk][c4]     = (_Float16)lo;
                        pa[kk][4 + c4] = (_Float16)hv;
                    }
                }
                // O += P . Ej
                #pragma unroll
                for (int nh = 0; nh < 2; ++nh)
                    #pragma unroll
                    for (int kk = 0; kk < 2; ++kk) {
                        const int ktj = 2 * mj + kk;
                        f16x8 bb = *(const f16x8*)(EB + (nh * 32 + l31) * 64 +
                                                   (((2 * ktj + hi) ^ (l31 & 7)) * 8));
                        oacc[mi][nh] = __builtin_amdgcn_mfma_f32_32x32x16_f16(
                            pa[kk], bb, oacc[mi][nh], 0, 0, 0);
                    }
            }
        }
    }

    // ---- epilogue: per-wave O.pwh partials -> LDS (aliases dead EA tile) ---
    float* pacc = (float*)&tiles[0][w][0];      // 64 floats, wave-private
    const float pwh0 = pred_w[64 + l31];
    const float pwh1 = pred_w[96 + l31];
    #pragma unroll
    for (int mi = 0; mi < 2; ++mi)
        #pragma unroll
        for (int r = 0; r < 16; ++r) {
            float v = oacc[mi][0][r] * pwh0 + oacc[mi][1][r] * pwh1;
            v += __shfl_xor(v, 1);  v += __shfl_xor(v, 2);  v += __shfl_xor(v, 4);
            v += __shfl_xor(v, 8);  v += __shfl_xor(v, 16);
            int i_loc = mi * 32 + 8 * (r >> 2) + (r & 3) + 4 * hi;
            if (l31 == 0) pacc[i_loc] = v;
        }
    __syncthreads();
    if (w == 0) {
        const float pb0 = pred_b[0];
        #pragma unroll
        for (int ni = 0; ni < 2; ++ni) {
            float dot = 0.f;
            #pragma unroll
            for (int kt = 0; kt < 4; ++kt)
                #pragma unroll
                for (int e = 0; e < 8; ++e)
                    dot = fmaf((float)eb[ni][kt][e], pred_w[16 * kt + 8 * hi + e], dot);
            dot += __shfl_xor(dot, 32);
            if (hi == 0) {
                int i_loc = ni * 32 + l31;
                int gi = it * 64 + i_loc;
                float osum = ((float*)&tiles[0][0][0])[i_loc] +
                             ((float*)&tiles[0][1][0])[i_loc] +
                             ((float*)&tiles[0][2][0])[i_loc] +
                             ((float*)&tiles[0][3][0])[i_loc];
                float dsum = 0.f;
                #pragma unroll
                for (int jj = 0; jj < 32; ++jj) dsum += degP[jj * 1024 + gi];
                preds[b * 1024 + gi] = dot + osum * fast_rcp(dsum) + pb0;
            }
        }
    }
}

extern "C" void kernel_launch(void* const* d_in, const int* in_sizes, int n_in,
                              void* d_out, int out_size, void* d_ws, size_t ws_size,
                              hipStream_t stream) {
    const float* x      = (const float*)d_in[0];
    const float* A      = (const float*)d_in[1];
    const float* Wih    = (const float*)d_in[2];
    const float* Whh    = (const float*)d_in[3];
    const float* bih    = (const float*)d_in[4];
    const float* bhh    = (const float*)d_in[5];
    const float* attn_w = (const float*)d_in[6];
    const float* attn_b = (const float*)d_in[7];
    const float* gnn_w  = (const float*)d_in[8];
    const float* gnn_b  = (const float*)d_in[9];
    const float* pred_w = (const float*)d_in[10];
    const float* pred_b = (const float*)d_in[11];
    float* preds = (float*)d_out;

    // ws: E16 (4MB) | ET (4MB) | coefQH (2MB) | degP (128KB)
    _Float16* E16    = (_Float16*)d_ws;
    _Float16* ET     = E16 + (size_t)BNc * Hc;
    _Float16* coefQH = ET + (size_t)BNc * Hc;
    float* degP      = (float*)(coefQH + (size_t)Nc * Nc);

    lstm_attn_kernel<<<BNc / 32, 128, 0, stream>>>(x, Wih, Whh, bih, bhh,
                                                   attn_w, attn_b, E16, ET);
    coefq_kernel<<<1024, 256, 0, stream>>>(A, gnn_w, gnn_b, coefQH, degP);
    gnn_pred_kernel<<<Bc * (Nc / 64), 256, 0, stream>>>(E16, ET, coefQH, degP,
                                                        pred_w, pred_b, preds);
}

// Round 12
// 211.986 us; speedup vs baseline: 1.1950x; 1.0279x over previous
//
#include <hip/hip_runtime.h>

// Problem constants (B,N,T,F,H,R) = (32,1024,32,5,64,5)
constexpr int Bc = 32, Nc = 1024, Tc = 32, Fc = 5, Hc = 64;
constexpr int BNc = Bc * Nc;   // 32768 sequences

#define DEVFN __device__ __forceinline__

typedef _Float16 f16x8 __attribute__((ext_vector_type(8)));
typedef _Float16 f16x4 __attribute__((ext_vector_type(4)));
typedef float    f32x16 __attribute__((ext_vector_type(16)));

DEVFN float fast_rcp(float x) { return __builtin_amdgcn_rcpf(x); }
DEVFN float tanh_fast(float x) { return 1.f - 2.f * fast_rcp(__expf(2.f * x) + 1.f); }

#if __has_builtin(__builtin_amdgcn_exp2f)
DEVFN float exp2_fast(float x) { return __builtin_amdgcn_exp2f(x); }
#else
DEVFN float exp2_fast(float x) { return exp2f(x); }
#endif

// ------------- Fused kernel: LSTM+attention (blocks 0..1023) ----------------
//                + edge-coefficient phase (blocks 1024..2047)
// The two phases are data-independent (lstm: x; coefq: A). coefq blocks fill
// the CU occupancy slots the latency-bound lstm leaves idle, hiding coefq's
// entire runtime and removing one serial dispatch.
// LSTM body = R9 exactly (best measured 112.9 µs): 2 waves x 32 seqs, wave
// owns 32 units, exp2-folded weights, fused-denominator cell algebra
// (5 exp2 + 2 rcp per unit), pitch-64 swizzled fp16 h-exchange.
__global__ __launch_bounds__(128, 2) void lstm_coefq_kernel(
    const float* __restrict__ x,      // [BN, T, F]
    const float* __restrict__ Wih,    // [4H, F]
    const float* __restrict__ Whh,    // [4H, H]
    const float* __restrict__ bih,    // [4H]
    const float* __restrict__ bhh,    // [4H]
    const float* __restrict__ attn_w, // [H]
    const float* __restrict__ attn_b, // [1]
    const float* __restrict__ A,      // [N, N, R]
    const float* __restrict__ gnn_w,  // [R]
    const float* __restrict__ gnn_b,  // [1]
    _Float16* __restrict__ E16,       // [B*N, H] fp16 row-major
    _Float16* __restrict__ ET,        // [B][H][N] fp16 transposed
    _Float16* __restrict__ coefQH,    // [N/4][N][4] fp16
    float* __restrict__ degP)         // [32][N] partial counts
{
    // LDS overlay: lstm uses 18.9 KB (xs 10496 | hb 8192 | ap 256);
    // coefq uses 21.0 KB (as 20736 | dcnt 256). Max = 20992 B.
    __shared__ __align__(16) char smem[20992];

    const int tid  = threadIdx.x;

    if (blockIdx.x >= 1024) {
        // =================== coefq phase (128 threads) ======================
        constexpr int CP = 162;                 // float pitch
        float* as   = (float*)smem;             // [32][162]
        float* dcnt = (float*)(smem + 20736);   // [2][32]
        const int cb = blockIdx.x - 1024;
        const int it = cb >> 5, jt = cb & 31;
        const int w    = tid >> 6;
        const int lane = tid & 63;

        float gw[5];
        #pragma unroll
        for (int f = 0; f < 5; ++f) gw[f] = gnn_w[f];
        const float gb = gnn_b[0];

        // stage 32 rows x 160 floats (coalesced float2)
        const float* src = A + ((size_t)it * 32 * 1024 + jt * 32) * 5;
        #pragma unroll
        for (int k = 0; k < 20; ++k) {
            int idx = tid + k * 128;            // 0..2559
            int row = idx / 80, c2 = idx - row * 80;
            *(float2*)&as[row * CP + c2 * 2] =
                *(const float2*)(src + (size_t)row * 5120 + c2 * 2);
        }
        __syncthreads();

        // thread (q2 = tid>>5, i_loc = tid&31) handles quads 2q2, 2q2+1
        const int q2 = tid >> 5, i_loc = tid & 31;
        float cnt = 0.f;
        #pragma unroll
        for (int gg2 = 0; gg2 < 2; ++gg2) {
            const int gg = 2 * q2 + gg2;
            float cf[4];
            #pragma unroll
            for (int q = 0; q < 4; ++q) {
                const float* ap_ = &as[i_loc * CP + (gg * 4 + q) * 5];
                float s = 0.f, d = gb;
                #pragma unroll
                for (int f = 0; f < 5; ++f) { float vv = ap_[f]; s += vv; d = fmaf(vv, gw[f], d); }
                cf[q] = (s > 0.f) ? (d >= 0.f ? d : 0.2f * d) : 0.f;
                cnt += (s > 0.f) ? 1.f : 0.f;
            }
            ((f16x4*)coefQH)[(size_t)(jt * 8 + gg) * 1024 + it * 32 + i_loc] =
                f16x4{(_Float16)cf[0], (_Float16)cf[1], (_Float16)cf[2], (_Float16)cf[3]};
        }
        // degree: combine q2 pairs within wave, then across waves via LDS
        cnt += __shfl_xor(cnt, 32);
        if (lane < 32) dcnt[w * 32 + i_loc] = cnt;
        __syncthreads();
        if (tid < 32)
            degP[jt * 1024 + it * 32 + tid] = dcnt[tid] + dcnt[32 + tid];
        return;
    }

    // ======================= LSTM + attention phase =========================
    constexpr int XP = 164;                     // x pitch (halves)
    _Float16* xs = (_Float16*)smem;             // [32][164]; aliased w/ es
    _Float16* hbp = (_Float16*)(smem + 10496);  // [2][32*64]
    float*    ap  = (float*)(smem + 10496 + 8192); // [2][32]
    float*    es  = (float*)xs;                 // [32][65] epilogue bounce

    const int w    = tid >> 6;                  // wave id (0,1)
    const int lane = tid & 63;
    const int m    = lane & 31;                 // seq column
    const int hi   = lane >> 5;

    // ---- stage x (fp32 -> fp16 LDS) ----
    const float* xg = x + (size_t)blockIdx.x * 32 * Tc * Fc;
    for (int i = tid; i < 32 * 160; i += 128) {
        int mm = i / 160, o = i - mm * 160;
        xs[mm * XP + o] = (_Float16)xg[i];
    }
    // zero h buffer 0
    for (int i = tid; i < 1024; i += 128) ((uint*)hbp)[i] = 0u;

    // per-gate exp2 folding scales (gate order i,f,g,o)
    constexpr float L2E = 1.4426950408889634f;
    const float gsc[4] = {-L2E, -L2E, 2.f * L2E, -L2E};

    // ---- preload A fragments: af[g][kt], jt = 2g+w, row j = 32*jt + m ----
    f16x8 af[4][5];
    #pragma unroll
    for (int g = 0; g < 4; ++g) {
        const int j = 32 * (2 * g + w) + m;     // = 64g + 32w + m
        const float sc = gsc[g];
        #pragma unroll
        for (int kt = 0; kt < 4; ++kt) {
            const float* wp = Whh + j * 64 + kt * 16 + 8 * hi;
            float4 u0 = *(const float4*)wp;
            float4 u1 = *(const float4*)(wp + 4);
            af[g][kt] = f16x8{(_Float16)(sc * u0.x), (_Float16)(sc * u0.y),
                              (_Float16)(sc * u0.z), (_Float16)(sc * u0.w),
                              (_Float16)(sc * u1.x), (_Float16)(sc * u1.y),
                              (_Float16)(sc * u1.z), (_Float16)(sc * u1.w)};
        }
        float v[8];
        #pragma unroll
        for (int e = 0; e < 5; ++e) v[e] = sc * Wih[j * Fc + e];
        v[5] = sc * (bih[j] + bhh[j]); v[6] = 0.f; v[7] = 0.f;
        #pragma unroll
        for (int e = 0; e < 8; ++e) {
            float z = hi ? 0.f : v[e];
            af[g][4][e] = (_Float16)z;
        }
    }

    // attention weights for owned units u = 32w + 8a2 + 4hi + p
    float aw_own[16];
    #pragma unroll
    for (int a2 = 0; a2 < 4; ++a2)
        #pragma unroll
        for (int p = 0; p < 4; ++p)
            aw_own[a2 * 4 + p] = attn_w[32 * w + 8 * a2 + 4 * hi + p];
    const float ab = attn_b[0];

    float hcur[16], cst[16], oacc[16];
    #pragma unroll
    for (int i = 0; i < 16; ++i) { hcur[i] = 0.f; cst[i] = 0.f; oacc[i] = 0.f; }
    float lsum = 0.f;

    f32x16 zero16 = {0,0,0,0,0,0,0,0,0,0,0,0,0,0,0,0};
    const int xrow = m * XP;
    const int swz  = m & 15;                    // chunk XOR swizzle
    __syncthreads();

    // ---- initial B fragments from hb[0] (zeros) + x(0) ----
    f16x8 bf[5];
    #pragma unroll
    for (int kt = 0; kt < 4; ++kt) {
        f16x4 lo = *(const f16x4*)&hbp[m * 64 + ((4 * kt + 2 * hi)     ^ swz) * 4];
        f16x4 hh = *(const f16x4*)&hbp[m * 64 + ((4 * kt + 2 * hi + 1) ^ swz) * 4];
        bf[kt] = f16x8{lo[0], lo[1], lo[2], lo[3], hh[0], hh[1], hh[2], hh[3]};
    }
    {
        #pragma unroll
        for (int e = 0; e < 8; ++e) bf[4][e] = (_Float16)0.f;
        if (!hi) {
            #pragma unroll
            for (int e = 0; e < 5; ++e) bf[4][e] = xs[xrow + e];
            bf[4][5] = (_Float16)1.f;
        }
    }

    #pragma unroll 1
    for (int t = 0; t < Tc; ++t) {
        // ---- gates: 4 gate tiles x 5 k-tiles ----
        f32x16 acc[4];
        #pragma unroll
        for (int g = 0; g < 4; ++g) {
            acc[g] = __builtin_amdgcn_mfma_f32_32x32x16_f16(af[g][0], bf[0], zero16, 0, 0, 0);
            #pragma unroll
            for (int kt = 1; kt < 5; ++kt)
                acc[g] = __builtin_amdgcn_mfma_f32_32x32x16_f16(af[g][kt], bf[kt], acc[g], 0, 0, 0);
        }
        // ---- cell update: 5 exp2 + 2 rcp per unit (weights pre-scaled) ----
        float attnp = 0.f;
        #pragma unroll
        for (int r = 0; r < 16; ++r) {
            float ei = exp2_fast(acc[0][r]);        // e^{-i}
            float ef = exp2_fast(acc[1][r]);        // e^{-f}
            float Eg = exp2_fast(acc[2][r]);        // e^{2g}
            float eo = exp2_fast(acc[3][r]);        // e^{-o}
            float u  = 1.f + ei;
            float v  = 1.f + ef;
            float wq = Eg + 1.f;
            float z  = Eg - 1.f;
            float t1 = u * wq;
            float num = fmaf(cst[r], t1, z * v);
            float cn = num * fast_rcp(t1 * v);
            cst[r] = cn;
            float E2 = exp2_fast(2.f * L2E * cn);   // e^{2c}
            float hv = (E2 - 1.f) * fast_rcp((E2 + 1.f) * (1.f + eo));
            hcur[r] = hv;
            attnp = fmaf(hv, aw_own[r], attnp);
        }
        // ---- publish h (fp16, swizzled chunks) + attention partial ----
        _Float16* hw = hbp + ((t + 1) & 1) * 2048;
        #pragma unroll
        for (int a2 = 0; a2 < 4; ++a2) {
            f16x4 pk = {(_Float16)hcur[4 * a2 + 0], (_Float16)hcur[4 * a2 + 1],
                        (_Float16)hcur[4 * a2 + 2], (_Float16)hcur[4 * a2 + 3]};
            *(f16x4*)&hw[m * 64 + ((8 * w + 2 * a2 + hi) ^ swz) * 4] = pk;
        }
        attnp += __shfl_xor(attnp, 32);
        if (!hi) ap[w * 32 + m] = attnp;
        __syncthreads();
        // ---- score + online accumulation (both waves identical) ----
        float sc = tanh_fast(ap[m] + ap[32 + m] + ab);
        float ew = __expf(sc);
        lsum += ew;
        #pragma unroll
        for (int i = 0; i < 16; ++i) oacc[i] = fmaf(ew, hcur[i], oacc[i]);
        // ---- build next B fragments ----
        if (t != Tc - 1) {
            const _Float16* hr = hbp + ((t + 1) & 1) * 2048;
            #pragma unroll
            for (int kt = 0; kt < 4; ++kt) {
                f16x4 lo = *(const f16x4*)&hr[m * 64 + ((4 * kt + 2 * hi)     ^ swz) * 4];
                f16x4 hh = *(const f16x4*)&hr[m * 64 + ((4 * kt + 2 * hi + 1) ^ swz) * 4];
                bf[kt] = f16x8{lo[0], lo[1], lo[2], lo[3], hh[0], hh[1], hh[2], hh[3]};
            }
            if (!hi) {
                #pragma unroll
                for (int e = 0; e < 5; ++e) bf[4][e] = xs[xrow + (t + 1) * Fc + e];
                bf[4][5] = (_Float16)1.f;
            }
        }
    }

    // ---- epilogue: es[m][u] = oacc/lsum, then E16 + ET ----
    __syncthreads();                    // xs reads done before aliasing
    const float li = fast_rcp(lsum);
    #pragma unroll
    for (int r = 0; r < 16; ++r) {
        int u = 32 * w + 8 * (r >> 2) + 4 * hi + (r & 3);
        es[m * 65 + u] = oacc[r] * li;
    }
    __syncthreads();

    uint* E16u = (uint*)E16 + (size_t)blockIdx.x * 32 * 32;
    for (int idx = tid; idx < 32 * 32; idx += 128) {
        int mm = idx >> 5, hp = idx & 31;
        union { _Float16 h2[2]; uint u; } cv;
        cv.h2[0] = (_Float16)es[mm * 65 + 2 * hp];
        cv.h2[1] = (_Float16)es[mm * 65 + 2 * hp + 1];
        E16u[idx] = cv.u;
    }
    const int bb_ = blockIdx.x >> 5, n0d = (blockIdx.x & 31) * 16;
    uint* ETu = (uint*)ET;
    for (int idx = tid; idx < 64 * 16; idx += 128) {
        int h = idx >> 4, c = idx & 15;
        union { _Float16 h2[2]; uint u; } cv;
        cv.h2[0] = (_Float16)es[(2 * c) * 65 + h];
        cv.h2[1] = (_Float16)es[(2 * c + 1) * 65 + h];
        ETu[((size_t)bb_ * 64 + h) * 512 + n0d + c] = cv.u;
    }
}

// ---------------- Kernel 3: MFMA GNN message pass + prediction head ---------
__global__ __launch_bounds__(256, 2) void gnn_pred_kernel(
    const _Float16* __restrict__ E16,  // [B*N, H]
    const _Float16* __restrict__ ET,   // [B][H][N]
    const _Float16* __restrict__ coefQH,// [N/4][N][4] fp16
    const float* __restrict__ degP,    // [32][N]
    const float* __restrict__ pred_w,  // [2H]
    const float* __restrict__ pred_b,  // [1]
    float* __restrict__ preds)         // [B*N]
{
    __shared__ __align__(16) _Float16 tiles[2][4][64 * 64];  // 64 KB exactly
    const int tid  = threadIdx.x;
    const int w    = tid >> 6;
    const int lane = tid & 63;
    const int l31  = lane & 31;
    const int hi   = lane >> 5;
    const int it   = blockIdx.x >> 5;           // it-major (XCD locality)
    const int b    = blockIdx.x & 31;

    _Float16* EA = &tiles[0][w][0];
    _Float16* EB = &tiles[1][w][0];
    const f16x4* cq = (const f16x4*)coefQH;

    f16x8 eb[2][4];
    #pragma unroll
    for (int ni = 0; ni < 2; ++ni)
        #pragma unroll
        for (int kt = 0; kt < 4; ++kt)
            eb[ni][kt] = *(const f16x8*)(E16 +
                ((size_t)(b * 1024 + it * 64 + ni * 32 + l31) * 64 + 16 * kt + 8 * hi));

    f32x16 zero16 = {0,0,0,0,0,0,0,0,0,0,0,0,0,0,0,0};
    f32x16 oacc[2][2];
    #pragma unroll
    for (int mi = 0; mi < 2; ++mi)
        #pragma unroll
        for (int nh = 0; nh < 2; ++nh) oacc[mi][nh] = zero16;

    #pragma unroll 1
    for (int s = 0; s < 4; ++s) {
        const int jt = w * 4 + s;
        const _Float16* srcA = E16 + (size_t)(b * 1024 + jt * 64) * 64;
        const _Float16* srcB = ET + (size_t)b * 64 * 1024 + jt * 64;
        #pragma unroll
        for (int q = 0; q < 8; ++q) {
            int f = q * 64 + lane, r = f >> 3, c = f & 7;
            uint4 va = *(const uint4*)(srcA + r * 64 + c * 8);
            *(uint4*)(EA + r * 64 + ((c ^ (r & 7)) * 8)) = va;
            uint4 vb = *(const uint4*)(srcB + r * 1024 + c * 8);
            *(uint4*)(EB + r * 64 + ((c ^ (r & 7)) * 8)) = vb;
        }
        #pragma unroll 1
        for (int mj = 0; mj < 2; ++mj) {
            f16x8 af[4];
            #pragma unroll
            for (int kt = 0; kt < 4; ++kt)
                af[kt] = *(const f16x8*)(EA + (mj * 32 + l31) * 64 +
                                         (((2 * kt + hi) ^ (l31 & 7)) * 8));
            #pragma unroll
            for (int mi = 0; mi < 2; ++mi) {
                // S' = Ej . Ei^T  (16 regs live)
                f32x16 a = __builtin_amdgcn_mfma_f32_32x32x16_f16(af[0], eb[mi][0], zero16, 0, 0, 0);
                #pragma unroll
                for (int kt = 1; kt < 4; ++kt)
                    a = __builtin_amdgcn_mfma_f32_32x32x16_f16(af[kt], eb[mi][kt], a, 0, 0, 0);
                // P = S' * coef (fp16 coef, 8B per lane)
                #pragma unroll
                for (int rg = 0; rg < 4; ++rg) {
                    int j0 = jt * 64 + mj * 32 + 8 * rg + 4 * hi;
                    f16x4 cfh = cq[(size_t)(j0 >> 2) * 1024 + it * 64 + mi * 32 + l31];
                    a[4 * rg + 0] *= (float)cfh[0]; a[4 * rg + 1] *= (float)cfh[1];
                    a[4 * rg + 2] *= (float)cfh[2]; a[4 * rg + 3] *= (float)cfh[3];
                }
                // pack C-layout -> fp16 A-frags via lane^32 swap
                f16x8 pa[2];
                #pragma unroll
                for (int kk = 0; kk < 2; ++kk) {
                    const int rg = 2 * kk;
                    #pragma unroll
                    for (int c4 = 0; c4 < 4; ++c4) {
                        float own_lo = a[rg * 4 + c4];
                        float own_hi = a[(rg + 1) * 4 + c4];
                        float send = hi ? own_lo : own_hi;
                        float recv = __shfl_xor(send, 32);
                        float lo = hi ? recv : own_lo;
                        float hv = hi ? own_hi : recv;
                        pa[kk][c4]     = (_Float16)lo;
                        pa[kk][4 + c4] = (_Float16)hv;
                    }
                }
                // O += P . Ej
                #pragma unroll
                for (int nh = 0; nh < 2; ++nh)
                    #pragma unroll
                    for (int kk = 0; kk < 2; ++kk) {
                        const int ktj = 2 * mj + kk;
                        f16x8 bb = *(const f16x8*)(EB + (nh * 32 + l31) * 64 +
                                                   (((2 * ktj + hi) ^ (l31 & 7)) * 8));
                        oacc[mi][nh] = __builtin_amdgcn_mfma_f32_32x32x16_f16(
                            pa[kk], bb, oacc[mi][nh], 0, 0, 0);
                    }
            }
        }
    }

    // ---- epilogue: per-wave O.pwh partials -> LDS (aliases dead EA tile) ---
    float* pacc = (float*)&tiles[0][w][0];      // 64 floats, wave-private
    const float pwh0 = pred_w[64 + l31];
    const float pwh1 = pred_w[96 + l31];
    #pragma unroll
    for (int mi = 0; mi < 2; ++mi)
        #pragma unroll
        for (int r = 0; r < 16; ++r) {
            float v = oacc[mi][0][r] * pwh0 + oacc[mi][1][r] * pwh1;
            v += __shfl_xor(v, 1);  v += __shfl_xor(v, 2);  v += __shfl_xor(v, 4);
            v += __shfl_xor(v, 8);  v += __shfl_xor(v, 16);
            int i_loc = mi * 32 + 8 * (r >> 2) + (r & 3) + 4 * hi;
            if (l31 == 0) pacc[i_loc] = v;
        }
    __syncthreads();
    if (w == 0) {
        const float pb0 = pred_b[0];
        #pragma unroll
        for (int ni = 0; ni < 2; ++ni) {
            float dot = 0.f;
            #pragma unroll
            for (int kt = 0; kt < 4; ++kt)
                #pragma unroll
                for (int e = 0; e < 8; ++e)
                    dot = fmaf((float)eb[ni][kt][e], pred_w[16 * kt + 8 * hi + e], dot);
            dot += __shfl_xor(dot, 32);
            if (hi == 0) {
                int i_loc = ni * 32 + l31;
                int gi = it * 64 + i_loc;
                float osum = ((float*)&tiles[0][0][0])[i_loc] +
                             ((float*)&tiles[0][1][0])[i_loc] +
                             ((float*)&tiles[0][2][0])[i_loc] +
                             ((float*)&tiles[0][3][0])[i_loc];
                float dsum = 0.f;
                #pragma unroll
                for (int jj = 0; jj < 32; ++jj) dsum += degP[jj * 1024 + gi];
                preds[b * 1024 + gi] = dot + osum * fast_rcp(dsum) + pb0;
            }
        }
    }
}

extern "C" void kernel_launch(void* const* d_in, const int* in_sizes, int n_in,
                              void* d_out, int out_size, void* d_ws, size_t ws_size,
                              hipStream_t stream) {
    const float* x      = (const float*)d_in[0];
    const float* A      = (const float*)d_in[1];
    const float* Wih    = (const float*)d_in[2];
    const float* Whh    = (const float*)d_in[3];
    const float* bih    = (const float*)d_in[4];
    const float* bhh    = (const float*)d_in[5];
    const float* attn_w = (const float*)d_in[6];
    const float* attn_b = (const float*)d_in[7];
    const float* gnn_w  = (const float*)d_in[8];
    const float* gnn_b  = (const float*)d_in[9];
    const float* pred_w = (const float*)d_in[10];
    const float* pred_b = (const float*)d_in[11];
    float* preds = (float*)d_out;

    // ws: E16 (4MB) | ET (4MB) | coefQH (2MB) | degP (128KB)
    _Float16* E16    = (_Float16*)d_ws;
    _Float16* ET     = E16 + (size_t)BNc * Hc;
    _Float16* coefQH = ET + (size_t)BNc * Hc;
    float* degP      = (float*)(coefQH + (size_t)Nc * Nc);

    lstm_coefq_kernel<<<2048, 128, 0, stream>>>(x, Wih, Whh, bih, bhh,
                                                attn_w, attn_b, A, gnn_w, gnn_b,
                                                E16, ET, coefQH, degP);
    gnn_pred_kernel<<<Bc * (Nc / 64), 256, 0, stream>>>(E16, ET, coefQH, degP,
                                                        pred_w, pred_b, preds);
}